// Round 2
// baseline (1845.794 us; speedup 1.0000x reference)
//
#include <hip/hip_runtime.h>
#include <hip/hip_cooperative_groups.h>
#include <math.h>

constexpr int cB = 8, cT = 2048, cDU = 512, cDM = 512, cDA = 256, cDF = 12, cL = 4;
constexpr float cEPS = 1e-6f;
constexpr float cSCALE = 16.0f;   // sqrt(DA)
constexpr float cGAMMA = 1.0f;

typedef unsigned short u16;
typedef unsigned char u8;
typedef u16 u16x8 __attribute__((ext_vector_type(8)));

// ---------------- workspace layout (float offsets) ----------------
constexpr size_t F_SB = 0;                 // sbias  B*T
constexpr size_t F_UN = F_SB + 16384;      // unorm2 B*T
constexpr size_t F_LG = F_UN + 16384;      // logits B*T
constexpr size_t F_Y  = F_LG + 16384;      // y (final, per stage) B*T
constexpr size_t F_PR = F_Y  + 16384;      // prev   B*T
constexpr size_t F_OV = F_PR + 16384;      // overlap B*T
constexpr size_t F_SP = F_OV + 16384;      // spread partials B*512
constexpr size_t F_QK = F_SP + 4096;       // qk  B*DU
constexpr size_t F_M0 = F_QK + 4096;       // memory buf 0
constexpr size_t F_M1 = F_M0 + 4096;       // memory buf 1
constexpr size_t F_C  = F_M1 + 4096;       // c_raw B*DU
constexpr size_t F_Z  = F_C  + 4096;       // z B*DU
constexpr size_t F_SC = F_Z  + 4096;       // scalars B*8
constexpr size_t F_BAR = F_SC + 64;        // 8 barrier counters, 256B apart (512 floats)
constexpr size_t F_A  = F_BAR + 512;       // A = Wk^T @ Wq, 512x512
constexpr size_t F_END = F_A + 262144;
constexpr size_t U_OFFB   = F_END * 4;                       // bf16 u
constexpr size_t U_BYTES  = (size_t)cB * cT * cDU * 2;
constexpr size_t S8_OFFB  = U_OFFB + U_BYTES;                // u8 sim
constexpr size_t S8_BYTES = (size_t)cB * cT * cT;
constexpr size_t WS_NEED_U   = S8_OFFB;
constexpr size_t WS_NEED_ALL = S8_OFFB + S8_BYTES;
// scal: 0 ysum_clamped, 1 coverage, 2 entropy, 3 wsq, 6 csq

__device__ __forceinline__ float wave_sum(float v) {
#pragma unroll
  for (int o = 32; o; o >>= 1) v += __shfl_down(v, o);
  return v;   // valid on lane 0
}
__device__ __forceinline__ float wave_max(float v) {
#pragma unroll
  for (int o = 32; o; o >>= 1) v = fmaxf(v, __shfl_down(v, o));
  return v;   // valid on lane 0
}
__device__ __forceinline__ float blk_max(float v, float* red, int wv, int lane) {
  v = wave_max(v);
  __syncthreads();
  if (lane == 0) red[wv] = v;
  __syncthreads();
  return fmaxf(fmaxf(red[0], red[1]), fmaxf(red[2], red[3]));
}
__device__ __forceinline__ float blk_sum(float v, float* red, int wv, int lane) {
  v = wave_sum(v);
  __syncthreads();
  if (lane == 0) red[wv] = v;
  __syncthreads();
  return red[0] + red[1] + red[2] + red[3];
}
__device__ __forceinline__ u16 f2bf(float f) {
  unsigned u = __float_as_uint(f);
  return (u16)((u + 0x7fffu + ((u >> 16) & 1u)) >> 16);
}
__device__ __forceinline__ float bf2f(u16 h) { return __uint_as_float(((unsigned)h) << 16); }
__device__ __forceinline__ float dot4(float4 a, float4 b) {
  return a.x * b.x + a.y * b.y + a.z * b.z + a.w * b.w;
}
__device__ __forceinline__ unsigned pack4(float a, float b, float c, float d) {
  unsigned b0 = (unsigned)(a * 255.f + 0.5f);
  unsigned b1 = (unsigned)(b * 255.f + 0.5f);
  unsigned b2 = (unsigned)(c * 255.f + 0.5f);
  unsigned b3 = (unsigned)(d * 255.f + 0.5f);
  return b0 | (b1 << 8) | (b2 << 16) | (b3 << 24);
}
__device__ __forceinline__ void dotu8(float& sd, unsigned w, float4 p) {
  sd += (float)(w & 255u) * p.x + (float)((w >> 8) & 255u) * p.y +
        (float)((w >> 16) & 255u) * p.z + (float)(w >> 24) * p.w;
}

// Per-group (per-b) monotonic barrier: arrive with release add; spin relaxed; acquire on exit.
__device__ __forceinline__ void gbar(unsigned* cnt, unsigned target) {
  __syncthreads();
  if (threadIdx.x == 0) {
    __hip_atomic_fetch_add(cnt, 1u, __ATOMIC_RELEASE, __HIP_MEMORY_SCOPE_AGENT);
    while (__hip_atomic_load(cnt, __ATOMIC_RELAXED, __HIP_MEMORY_SCOPE_AGENT) < target)
      __builtin_amdgcn_s_sleep(2);
  }
  __syncthreads();
  __threadfence();   // acquire: subsequent loads see peer blocks' writes
}

// ==== k_init: blocks 0..1023 mem0 copy + u->bf16 + sbias/unorm2 + zero barriers;
//      blocks 1024..1087: A = Wk^T @ Wq ====
__global__ __launch_bounds__(256) void k_init(
    const float* __restrict__ u, const float* __restrict__ sf,
    const float* __restrict__ mem0,
    const float* __restrict__ Wq, const float* __restrict__ Wk,
    const float* __restrict__ w1, const float* __restrict__ b1,
    const float* __restrict__ w2, const float* __restrict__ b2,
    float* __restrict__ wsf, u16* __restrict__ ubf, int use_ubf) {
  const int tid = threadIdx.x;
  if (blockIdx.x >= 1024) {
    __shared__ float wkj[32][8];
    int j0 = (blockIdx.x - 1024) * 8;
    float acc[8][2] = {};
    for (int a0 = 0; a0 < cDA; a0 += 32) {
      wkj[tid >> 3][tid & 7] = Wk[(size_t)(a0 + (tid >> 3)) * cDU + j0 + (tid & 7)];
      __syncthreads();
#pragma unroll 8
      for (int aa = 0; aa < 32; ++aa) {
        float wq0 = Wq[(size_t)(a0 + aa) * cDM + tid * 2];
        float wq1 = Wq[(size_t)(a0 + aa) * cDM + tid * 2 + 1];
#pragma unroll
        for (int r = 0; r < 8; ++r) {
          acc[r][0] += wkj[aa][r] * wq0;
          acc[r][1] += wkj[aa][r] * wq1;
        }
      }
      __syncthreads();
    }
#pragma unroll
    for (int r = 0; r < 8; ++r) {
      wsf[F_A + (size_t)(j0 + r) * cDU + tid * 2] = acc[r][0];
      wsf[F_A + (size_t)(j0 + r) * cDU + tid * 2 + 1] = acc[r][1];
    }
    return;
  }
  const int gt = blockIdx.x * 256 + tid;
  const int nt = 1024 * 256;
  const int wv = tid >> 6, lane = tid & 63;
  const int gw = blockIdx.x * 4 + wv;
  const int nwv = 1024 * 4;

  for (int i = gt; i < cB * cDM; i += nt) wsf[F_M0 + i] = mem0[i];
  for (int i = gt; i < 512; i += nt) wsf[F_BAR + i] = 0.f;   // zero barrier counters

  if (use_ubf) {
    const int NU8 = cB * cT * cDU / 8;
    const float4* src = (const float4*)u;
    for (int c = gt; c < NU8; c += nt) {
      float4 f0 = src[(size_t)c * 2], f1 = src[(size_t)c * 2 + 1];
      u16x8 o;
      o[0] = f2bf(f0.x); o[1] = f2bf(f0.y); o[2] = f2bf(f0.z); o[3] = f2bf(f0.w);
      o[4] = f2bf(f1.x); o[5] = f2bf(f1.y); o[6] = f2bf(f1.z); o[7] = f2bf(f1.w);
      *(u16x8*)(ubf + (size_t)c * 8) = o;
    }
  }
  for (int row = gw; row < cB * cT; row += nwv) {
    float d0 = sf[(size_t)row * cDF + 8];
    float d1 = sf[(size_t)row * cDF + 9];
    float d2 = sf[(size_t)row * cDF + 10];
    float acc = 0.f;
#pragma unroll
    for (int i = 0; i < 4; ++i) {
      int a = lane * 4 + i;
      float h = d0 * w1[a * 3 + 0] + d1 * w1[a * 3 + 1] + d2 * w1[a * 3 + 2] + b1[a];
      float g = 0.5f * h * (1.0f + erff(h * 0.70710678118654752f));
      acc += g * w2[a];
    }
    float un = 0.f;
    const float4* ur = (const float4*)(u + (size_t)row * cDU);
#pragma unroll
    for (int m = 0; m < 2; ++m) { float4 x = ur[lane + m * 64]; un += dot4(x, x); }
    acc = wave_sum(acc);
    un = wave_sum(un);
    if (lane == 0) { wsf[F_SB + row] = acc + b2[0]; wsf[F_UN + row] = un; }
  }
}

// ==== k_main: whole 4-stage loop; 8 independent per-b block groups with custom barriers
__global__ __launch_bounds__(256, 4) void k_main(
    const float* __restrict__ u, const float* __restrict__ sim,
    const float* __restrict__ logt, const float* __restrict__ Wv,
    const float* __restrict__ W_ih, const float* __restrict__ b_ih,
    const float* __restrict__ W_hh, const float* __restrict__ b_hh,
    float* __restrict__ ws, u16* __restrict__ ubf, u8* __restrict__ sim8,
    float* __restrict__ out, int use_ubf, int use_s8) {
  __shared__ float lds[4104];          // [0..2175] ylds / [2048..4095] comb / [4096..] red
  float* red = lds + 4096;
  const int tid = threadIdx.x;
  const int wv = tid >> 6, lane = tid & 63;
  const int G = gridDim.x >> 3;         // blocks per group (per b)
  const int b = blockIdx.x / G;         // batch index  (grid is multiple of 8)
  const int gb = blockIdx.x - b * G;    // block index within group
  const int gw = gb * 4 + wv;           // wave id within group
  const int GW = G * 4;                 // waves per group
  unsigned* cnt = (unsigned*)(ws + F_BAR) + (size_t)b * 64;   // 256B-spaced counters
  unsigned gen = 0;

  const float temp = fminf(fmaxf(expf(logt[0]), 0.1f), 10.0f);

  for (int stage = 0; stage < cL; ++stage) {
    float* mcur = ws + ((stage & 1) ? F_M1 : F_M0);
    float* mnxt = ws + ((stage & 1) ? F_M0 : F_M1);
    const int convert = (stage == 0 && use_s8) ? 1 : 0;

    // ---------- phase A: qk[b,:] = A @ mem[b,:]; zero c_raw[b,:] ----------
    for (int j = gw; j < cDM; j += GW) {
      const float4* ar = (const float4*)(ws + F_A + (size_t)j * cDM);
      const float4* mr = (const float4*)(mcur + (size_t)b * cDM);
      float acc = dot4(ar[lane * 2], mr[lane * 2]) + dot4(ar[lane * 2 + 1], mr[lane * 2 + 1]);
      acc = wave_sum(acc);
      if (lane == 0) ws[F_QK + b * cDU + j] = acc;
    }
    for (int t = gb * 256 + tid; t < cDU; t += G * 256) ws[F_C + b * cDU + t] = 0.f;
    ++gen; gbar(cnt, gen * G);

    // ---------- phase B: logits[b,:] ----------
    for (int s = gw; s < 512; s += GW) {
      const float4* qk4 = (const float4*)(ws + F_QK + (size_t)b * cDU);
      float4 q0 = qk4[lane * 2], q1 = qk4[lane * 2 + 1];
      float4 pv[8];
      if (stage > 0 && use_s8) {
        const float4* pr4 = (const float4*)(ws + F_PR + (size_t)b * cT);
#pragma unroll
        for (int m = 0; m < 2; ++m)
#pragma unroll
          for (int k = 0; k < 4; ++k) pv[m * 4 + k] = pr4[m * 256 + lane * 4 + k];
      }
#pragma unroll
      for (int i = 0; i < 4; ++i) {
        int grow = b * cT + s * 4 + i;
        float acc;
        if (use_ubf) {
          u16x8 sv = *(const u16x8*)(ubf + (size_t)grow * cDU + lane * 8);
          acc = bf2f(sv[0]) * q0.x + bf2f(sv[1]) * q0.y + bf2f(sv[2]) * q0.z + bf2f(sv[3]) * q0.w +
                bf2f(sv[4]) * q1.x + bf2f(sv[5]) * q1.y + bf2f(sv[6]) * q1.z + bf2f(sv[7]) * q1.w;
        } else {
          const float4* ur = (const float4*)(u + (size_t)grow * cDU);
          acc = dot4(ur[lane * 2], q0) + dot4(ur[lane * 2 + 1], q1);
        }
        acc *= (1.0f / cSCALE);
        if (stage > 0) {
          float sd = 0.f;
          if (use_s8) {
            const u8* sr = sim8 + (size_t)grow * cT;
            uint4 sq0 = *(const uint4*)(sr + lane * 16);
            uint4 sq1 = *(const uint4*)(sr + 1024 + lane * 16);
            dotu8(sd, sq0.x, pv[0]); dotu8(sd, sq0.y, pv[1]);
            dotu8(sd, sq0.z, pv[2]); dotu8(sd, sq0.w, pv[3]);
            dotu8(sd, sq1.x, pv[4]); dotu8(sd, sq1.y, pv[5]);
            dotu8(sd, sq1.z, pv[6]); dotu8(sd, sq1.w, pv[7]);
            sd *= (1.0f / 255.0f);
          } else {
            const float4* sr = (const float4*)(sim + (size_t)grow * cT);
            const float4* pr4 = (const float4*)(ws + F_PR + (size_t)b * cT);
#pragma unroll
            for (int m = 0; m < 8; ++m) sd += dot4(sr[lane + m * 64], pr4[lane + m * 64]);
          }
          acc -= cGAMMA * sd;
        }
        acc = wave_sum(acc);
        if (lane == 0) ws[F_LG + grow] = (acc + ws[F_SB + grow]) / temp;
      }
    }
    ++gen; gbar(cnt, gen * G);

    // ---------- phase C: softmax(logits[b,:]) + overlap = sim @ y1 (+stage-0 convert) --
    for (int ch = gb; ch < 128; ch += G) {
      float l[8];
      float mx = -INFINITY;
#pragma unroll
      for (int e = 0; e < 8; ++e) { l[e] = ws[F_LG + b * cT + e * 256 + tid]; mx = fmaxf(mx, l[e]); }
      mx = blk_max(mx, red, wv, lane);
      float sum = 0.f;
#pragma unroll
      for (int e = 0; e < 8; ++e) {
        float ev = expf(l[e] - mx);
        sum += ev;
        int sidx = e * 256 + tid;
        lds[sidx + (sidx >> 4)] = ev;
      }
      sum = blk_sum(sum, red, wv, lane);
      float invS = 1.f / sum;
      for (int r = 0; r < 4; ++r) {
        int row = b * cT + ch * 16 + wv * 4 + r;
        float acc = 0.f;
        if (use_s8 && !convert) {
          const u8* sr = sim8 + (size_t)row * cT;
#pragma unroll
          for (int m = 0; m < 2; ++m) {
            uint4 sq = *(const uint4*)(sr + m * 1024 + lane * 16);
            int s0 = m * 1024 + lane * 16;
#pragma unroll
            for (int k = 0; k < 4; ++k) {
              unsigned w = (&sq.x)[k];
              int si = s0 + k * 4;
              acc += (float)(w & 255u)         * lds[si + (si >> 4)] +
                     (float)((w >> 8) & 255u)  * lds[(si + 1) + ((si + 1) >> 4)] +
                     (float)((w >> 16) & 255u) * lds[(si + 2) + ((si + 2) >> 4)] +
                     (float)(w >> 24)          * lds[(si + 3) + ((si + 3) >> 4)];
            }
          }
          acc *= (1.0f / 255.0f);
        } else {
          const float4* sr = (const float4*)(sim + (size_t)row * cT);
#pragma unroll
          for (int m = 0; m < 2; ++m) {
            uint4 oq;
#pragma unroll
            for (int k = 0; k < 4; ++k) {
              float4 sv = sr[m * 256 + lane * 4 + k];
              int si = m * 1024 + lane * 16 + k * 4;
              acc += sv.x * lds[si + (si >> 4)] + sv.y * lds[(si + 1) + ((si + 1) >> 4)] +
                     sv.z * lds[(si + 2) + ((si + 2) >> 4)] + sv.w * lds[(si + 3) + ((si + 3) >> 4)];
              (&oq.x)[k] = pack4(sv.x, sv.y, sv.z, sv.w);
            }
            if (convert)
              *(uint4*)(sim8 + (size_t)row * cT + m * 1024 + lane * 16) = oq;
          }
        }
        acc = wave_sum(acc);
        if (lane == 0) ws[F_OV + row] = acc * invS;
      }
    }
    ++gen; gbar(cnt, gen * G);

    // ---------- phase D: penalty + resoftmax + stats + centroid accumulate ----------
    for (int ch = gb; ch < 128; ch += G) {
      float o[8], l[8], yv8[8];
      float mo = -INFINITY;
#pragma unroll
      for (int e = 0; e < 8; ++e) { o[e] = ws[F_OV + b * cT + e * 256 + tid]; mo = fmaxf(mo, o[e]); }
      mo = fmaxf(blk_max(mo, red, wv, lane), cEPS);
      float ml = -INFINITY;
#pragma unroll
      for (int e = 0; e < 8; ++e) { l[e] = ws[F_LG + b * cT + e * 256 + tid] - o[e] / mo; ml = fmaxf(ml, l[e]); }
      ml = blk_max(ml, red, wv, lane);
      float sum = 0.f;
#pragma unroll
      for (int e = 0; e < 8; ++e) { l[e] = expf(l[e] - ml); sum += l[e]; }
      sum = blk_sum(sum, red, wv, lane);
      float inv = 1.f / sum;
      float ysr_p = 0.f, wsq_p = 0.f;
#pragma unroll
      for (int e = 0; e < 8; ++e) {
        yv8[e] = l[e] * inv;
        lds[e * 256 + tid] = yv8[e];
        ysr_p += yv8[e];
        wsq_p += yv8[e] * ws[F_UN + b * cT + e * 256 + tid];
      }
      float ysr = blk_sum(ysr_p, red, wv, lane);
      float ysc = fmaxf(ysr, cEPS);
      float wsq = blk_sum(wsq_p, red, wv, lane);
      float ent_p = 0.f;
#pragma unroll
      for (int e = 0; e < 8; ++e) {
        float yn = yv8[e] / ysc;
        ent_p -= yn * logf(fmaxf(yn, cEPS));
      }
      float ent = blk_sum(ent_p, red, wv, lane);
      if (ch == 0) {
#pragma unroll
        for (int e = 0; e < 8; ++e) {
          int idx = b * cT + e * 256 + tid;
          ws[F_Y + idx] = yv8[e];
          if (stage == 0) ws[F_PR + idx] = yv8[e]; else ws[F_PR + idx] += yv8[e];
        }
        if (tid == 0) {
          ws[F_SC + b * 8 + 0] = ysc;
          ws[F_SC + b * 8 + 1] = ysr / (float)cT;
          ws[F_SC + b * 8 + 2] = ent;
          ws[F_SC + b * 8 + 3] = wsq;
        }
      }
      float acc[8] = {};
      for (int i = 0; i < 4; ++i) {
        int r = ch * 16 + wv * 4 + i;
        float yvv = lds[r];
        int row = b * cT + r;
        if (use_ubf) {
          u16x8 s8v = *(const u16x8*)(ubf + (size_t)row * cDU + lane * 8);
#pragma unroll
          for (int e = 0; e < 8; ++e) acc[e] += yvv * bf2f(s8v[e]);
        } else {
          const float4* ur = (const float4*)(u + (size_t)row * cDU);
          float4 a0 = ur[lane * 2], a1 = ur[lane * 2 + 1];
          acc[0] += yvv * a0.x; acc[1] += yvv * a0.y; acc[2] += yvv * a0.z; acc[3] += yvv * a0.w;
          acc[4] += yvv * a1.x; acc[5] += yvv * a1.y; acc[6] += yvv * a1.z; acc[7] += yvv * a1.w;
        }
      }
      __syncthreads();
#pragma unroll
      for (int e = 0; e < 8; ++e) lds[2048 + wv * 512 + lane * 8 + e] = acc[e];
      __syncthreads();
      float s0 = lds[2048 + tid] + lds[2048 + 512 + tid] + lds[2048 + 1024 + tid] + lds[2048 + 1536 + tid];
      float s1 = lds[2048 + tid + 256] + lds[2048 + 512 + tid + 256] +
                 lds[2048 + 1024 + tid + 256] + lds[2048 + 1536 + tid + 256];
      atomicAdd(&ws[F_C + b * cDU + tid], s0);
      atomicAdd(&ws[F_C + b * cDU + tid + 256], s1);
      __syncthreads();
    }
    ++gen; gbar(cnt, gen * G);

    // ---------- phase E: z[b,:] = c_raw @ Wv^T ; spread partials ----------
    for (int j = gw; j < cDU; j += GW) {
      const float4* c4 = (const float4*)(ws + F_C + (size_t)b * cDU);
      const float4* w4 = (const float4*)(Wv + (size_t)j * cDU);
      float acc = dot4(c4[lane * 2], w4[lane * 2]) + dot4(c4[lane * 2 + 1], w4[lane * 2 + 1]);
      acc = wave_sum(acc);
      if (lane == 0) ws[F_Z + b * cDU + j] = acc;
    }
    for (int s = gw; s < 512; s += GW) {
      float ysc = ws[F_SC + b * 8 + 0];
      float inv = 1.f / ysc;
      const float4* c4 = (const float4*)(ws + F_C + (size_t)b * cDU);
      float4 cr0 = c4[lane * 2], cr1 = c4[lane * 2 + 1];
      float4 cx0, cx1;
      cx0.x = cr0.x * inv; cx0.y = cr0.y * inv; cx0.z = cr0.z * inv; cx0.w = cr0.w * inv;
      cx1.x = cr1.x * inv; cx1.y = cr1.y * inv; cx1.z = cr1.z * inv; cx1.w = cr1.w * inv;
      float cen2 = wave_sum(dot4(cx0, cx0) + dot4(cx1, cx1));   // lane0-valid
      if (s == 0) {
        float csq = wave_sum(dot4(cr0, cr0) + dot4(cr1, cr1));
        if (lane == 0) ws[F_SC + b * 8 + 6] = csq;
      }
      float part = 0.f;
      for (int i = 0; i < 4; ++i) {
        int row = b * cT + s * 4 + i;
        float dot;
        if (use_ubf) {
          u16x8 sv = *(const u16x8*)(ubf + (size_t)row * cDU + lane * 8);
          dot = bf2f(sv[0]) * cx0.x + bf2f(sv[1]) * cx0.y + bf2f(sv[2]) * cx0.z + bf2f(sv[3]) * cx0.w +
                bf2f(sv[4]) * cx1.x + bf2f(sv[5]) * cx1.y + bf2f(sv[6]) * cx1.z + bf2f(sv[7]) * cx1.w;
        } else {
          const float4* ur = (const float4*)(u + (size_t)row * cDU);
          dot = dot4(ur[lane * 2], cx0) + dot4(ur[lane * 2 + 1], cx1);
        }
        dot = wave_sum(dot);
        if (lane == 0) {
          float d2 = ws[F_UN + row] - 2.f * dot + cen2;
          part += ws[F_Y + row] * sqrtf(fmaxf(d2, 0.f));
        }
      }
      if (lane == 0) ws[F_SP + b * 512 + s] = part;
    }
    ++gen; gbar(cnt, gen * G);

    // ---------- phase F: GRU gates + memory update + output ----------
    for (int t = gw; t < cDM; t += GW) {
      int i = t;
      const float4* xz = (const float4*)(ws + F_Z + (size_t)b * cDU);
      const float4* xm = (const float4*)(mcur + (size_t)b * cDM);
      float4 z0 = xz[lane * 2], z1 = xz[lane * 2 + 1];
      float4 m0 = xm[lane * 2], m1 = xm[lane * 2 + 1];
      float ysc = ws[F_SC + b * 8 + 0];
      float sv_ = 0.f;
#pragma unroll
      for (int k2 = 0; k2 < 8; ++k2) sv_ += ws[F_SP + b * 512 + lane * 8 + k2];
      float spr_raw = wave_sum(sv_);
      float aI[3], aH[3];
#pragma unroll
      for (int g = 0; g < 3; ++g) {
        size_t rrow = (size_t)(g * 512 + i);
        const float4* wI = (const float4*)(W_ih + rrow * 516);
        float a = dot4(z0, wI[lane * 2]) + dot4(z1, wI[lane * 2 + 1]);
        if (lane == 0) {
          float4 wt = wI[128];
          float cov = ws[F_SC + b * 8 + 1], ent = ws[F_SC + b * 8 + 2];
          float spr = spr_raw / ysc;
          float cmp = 2.f * (ysc * ws[F_SC + b * 8 + 3] - ws[F_SC + b * 8 + 6]) / fmaxf(ysc * ysc, cEPS);
          a += cov * wt.x + ent * wt.y + spr * wt.z + cmp * wt.w;
        }
        aI[g] = wave_sum(a);
        const float4* wH = (const float4*)(W_hh + rrow * cDM);
        float h = dot4(m0, wH[lane * 2]) + dot4(m1, wH[lane * 2 + 1]);
        aH[g] = wave_sum(h);
      }
      if (lane == 0) {
        float gir = aI[0] + b_ih[i],        ghr = aH[0] + b_hh[i];
        float giz = aI[1] + b_ih[512 + i],  ghz = aH[1] + b_hh[512 + i];
        float gin = aI[2] + b_ih[1024 + i], ghn = aH[2] + b_hh[1024 + i];
        float rg = 1.f / (1.f + expf(-(gir + ghr)));
        float zg = 1.f / (1.f + expf(-(giz + ghz)));
        float ng = tanhf(gin + rg * ghn);
        float mold = mcur[b * cDM + i];
        mnxt[b * cDM + i] = (1.f - zg) * ng + zg * mold;
        out[(size_t)(b * cL + stage) * cDU + i] = ws[F_Z + b * cDU + i];
      }
    }
    if (stage < cL - 1) { ++gen; gbar(cnt, gen * G); }
  }
}

extern "C" void kernel_launch(void* const* d_in, const int* in_sizes, int n_in,
                              void* d_out, int out_size, void* d_ws, size_t ws_size,
                              hipStream_t stream) {
  const float* u    = (const float*)d_in[0];
  const float* sf   = (const float*)d_in[1];
  const float* sim  = (const float*)d_in[2];
  const float* mem0 = (const float*)d_in[3];
  const float* Wq   = (const float*)d_in[4];
  const float* Wk   = (const float*)d_in[5];
  const float* Wv   = (const float*)d_in[6];
  const float* sbw1 = (const float*)d_in[7];
  const float* sbb1 = (const float*)d_in[8];
  const float* sbw2 = (const float*)d_in[9];
  const float* sbb2 = (const float*)d_in[10];
  const float* logt = (const float*)d_in[11];
  const float* W_ih = (const float*)d_in[12];
  const float* b_ih = (const float*)d_in[13];
  const float* W_hh = (const float*)d_in[14];
  const float* b_hh = (const float*)d_in[15];
  float* out = (float*)d_out;
  float* ws  = (float*)d_ws;
  u16* ubf  = (u16*)((char*)d_ws + U_OFFB);
  u8* sim8  = (u8*)((char*)d_ws + S8_OFFB);

  int use_ubf = (ws_size >= WS_NEED_U) ? 1 : 0;
  int use_s8  = (ws_size >= WS_NEED_ALL) ? 1 : 0;

  k_init<<<1088, 256, 0, stream>>>(u, sf, mem0, Wq, Wk, sbw1, sbb1, sbw2, sbb2,
                                   ws, ubf, use_ubf);

  // Cooperative grid (co-residency guarantee for spin barriers). Grid-stride phase
  // maps make any multiple-of-8 grid correct.
  static int nblk = 0;
  if (nblk == 0) {
    int occ = 0;
    if (hipOccupancyMaxActiveBlocksPerMultiprocessor(&occ, (const void*)k_main, 256, 0) != hipSuccess || occ <= 0)
      occ = 1;
    nblk = occ * 256;              // 256 CUs on MI355X
    if (nblk > 1024) nblk = 1024;
    if (nblk < 8) nblk = 8;
    nblk &= ~7;                    // multiple of 8 (one group per batch b)
  }
  void* kargs[] = {(void*)&u, (void*)&sim, (void*)&logt, (void*)&Wv,
                   (void*)&W_ih, (void*)&b_ih, (void*)&W_hh, (void*)&b_hh,
                   (void*)&ws, (void*)&ubf, (void*)&sim8, (void*)&out,
                   (void*)&use_ubf, (void*)&use_s8};
  hipLaunchCooperativeKernel((const void*)k_main, dim3(nblk), dim3(256), kargs, 0, stream);
}

// Round 3
// 1139.448 us; speedup vs baseline: 1.6199x; 1.6199x over previous
//
#include <hip/hip_runtime.h>
#include <hip/hip_cooperative_groups.h>
#include <math.h>

constexpr int cB = 8, cT = 2048, cDU = 512, cDM = 512, cDA = 256, cDF = 12, cL = 4;
constexpr float cEPS = 1e-6f;
constexpr float cSCALE = 16.0f;   // sqrt(DA)
constexpr float cGAMMA = 1.0f;

typedef unsigned short u16;
typedef unsigned char u8;
typedef u16 u16x8 __attribute__((ext_vector_type(8)));

// ---------------- workspace layout (float offsets) ----------------
constexpr size_t F_SB = 0;                 // sbias  B*T
constexpr size_t F_UN = F_SB + 16384;      // unorm2 B*T
constexpr size_t F_LG = F_UN + 16384;      // logits B*T
constexpr size_t F_Y  = F_LG + 16384;      // y (final, per stage) B*T
constexpr size_t F_PR = F_Y  + 16384;      // prev   B*T
constexpr size_t F_OV = F_PR + 16384;      // overlap B*T
constexpr size_t F_SP = F_OV + 16384;      // spread partials B*512
constexpr size_t F_QK = F_SP + 4096;       // qk  B*DU
constexpr size_t F_M0 = F_QK + 4096;       // memory buf 0
constexpr size_t F_M1 = F_M0 + 4096;       // memory buf 1
constexpr size_t F_C  = F_M1 + 4096;       // c_raw B*DU
constexpr size_t F_Z  = F_C  + 4096;       // z B*DU
constexpr size_t F_SC = F_Z  + 4096;       // scalars B*8
constexpr size_t F_BAR = F_SC + 64;        // 8 barrier counters, 256B apart (512 floats)
constexpr size_t F_A  = F_BAR + 512;       // A = Wk^T @ Wq, 512x512
constexpr size_t F_END = F_A + 262144;
constexpr size_t U_OFFB   = F_END * 4;                       // bf16 u
constexpr size_t U_BYTES  = (size_t)cB * cT * cDU * 2;
constexpr size_t S8_OFFB  = U_OFFB + U_BYTES;                // u8 sim
constexpr size_t S8_BYTES = (size_t)cB * cT * cT;
constexpr size_t WS_NEED_U   = S8_OFFB;
constexpr size_t WS_NEED_ALL = S8_OFFB + S8_BYTES;
// scal: 0 ysum_clamped, 1 coverage, 2 entropy, 3 wsq, 6 csq

__device__ __forceinline__ float wave_sum(float v) {
#pragma unroll
  for (int o = 32; o; o >>= 1) v += __shfl_down(v, o);
  return v;   // valid on lane 0
}
__device__ __forceinline__ float wave_max(float v) {
#pragma unroll
  for (int o = 32; o; o >>= 1) v = fmaxf(v, __shfl_down(v, o));
  return v;   // valid on lane 0
}
__device__ __forceinline__ float blk_max(float v, float* red, int wv, int lane) {
  v = wave_max(v);
  __syncthreads();
  if (lane == 0) red[wv] = v;
  __syncthreads();
  return fmaxf(fmaxf(red[0], red[1]), fmaxf(red[2], red[3]));
}
__device__ __forceinline__ float blk_sum(float v, float* red, int wv, int lane) {
  v = wave_sum(v);
  __syncthreads();
  if (lane == 0) red[wv] = v;
  __syncthreads();
  return red[0] + red[1] + red[2] + red[3];
}
__device__ __forceinline__ u16 f2bf(float f) {
  unsigned u = __float_as_uint(f);
  return (u16)((u + 0x7fffu + ((u >> 16) & 1u)) >> 16);
}
__device__ __forceinline__ float bf2f(u16 h) { return __uint_as_float(((unsigned)h) << 16); }
__device__ __forceinline__ float dot4(float4 a, float4 b) {
  return a.x * b.x + a.y * b.y + a.z * b.z + a.w * b.w;
}
__device__ __forceinline__ unsigned pack4(float a, float b, float c, float d) {
  unsigned b0 = (unsigned)(a * 255.f + 0.5f);
  unsigned b1 = (unsigned)(b * 255.f + 0.5f);
  unsigned b2 = (unsigned)(c * 255.f + 0.5f);
  unsigned b3 = (unsigned)(d * 255.f + 0.5f);
  return b0 | (b1 << 8) | (b2 << 16) | (b3 << 24);
}
__device__ __forceinline__ void dotu8p(float& sd, unsigned w, const float* p) {
  sd += (float)(w & 255u) * p[0] + (float)((w >> 8) & 255u) * p[1] +
        (float)((w >> 16) & 255u) * p[2] + (float)(w >> 24) * p[3];
}

// ---- coherent (agent-scope, per-access) communication ops: no cache-wide fences ----
__device__ __forceinline__ float gload(const float* p) {
  return __uint_as_float(__hip_atomic_load((const unsigned*)p, __ATOMIC_RELAXED,
                                           __HIP_MEMORY_SCOPE_AGENT));
}
__device__ __forceinline__ void gstore(float* p, float v) {
  __hip_atomic_store((unsigned*)p, __float_as_uint(v), __ATOMIC_RELAXED,
                     __HIP_MEMORY_SCOPE_AGENT);
}
__device__ __forceinline__ void gstore_u32(unsigned* p, unsigned v) {
  __hip_atomic_store(p, v, __ATOMIC_RELAXED, __HIP_MEMORY_SCOPE_AGENT);
}

// Per-group (per-b) barrier. Arrive: RELEASE add (drains our stores to the coherent
// point; no invalidation). Spin: relaxed. Exit: NO acquire fence — all cross-block
// reads are themselves agent-scoped loads, individually coherent.
__device__ __forceinline__ void gbar(unsigned* cnt, unsigned target) {
  __syncthreads();
  if (threadIdx.x == 0) {
    __hip_atomic_fetch_add(cnt, 1u, __ATOMIC_RELEASE, __HIP_MEMORY_SCOPE_AGENT);
    while (__hip_atomic_load(cnt, __ATOMIC_RELAXED, __HIP_MEMORY_SCOPE_AGENT) < target)
      __builtin_amdgcn_s_sleep(4);
  }
  __syncthreads();
}

// ==== k_init: blocks 0..1023 mem0 copy + u->bf16 + sbias/unorm2 + zero barriers;
//      blocks 1024..1087: A = Wk^T @ Wq ====
__global__ __launch_bounds__(256) void k_init(
    const float* __restrict__ u, const float* __restrict__ sf,
    const float* __restrict__ mem0,
    const float* __restrict__ Wq, const float* __restrict__ Wk,
    const float* __restrict__ w1, const float* __restrict__ b1,
    const float* __restrict__ w2, const float* __restrict__ b2,
    float* __restrict__ wsf, u16* __restrict__ ubf, int use_ubf) {
  const int tid = threadIdx.x;
  if (blockIdx.x >= 1024) {
    __shared__ float wkj[32][8];
    int j0 = (blockIdx.x - 1024) * 8;
    float acc[8][2] = {};
    for (int a0 = 0; a0 < cDA; a0 += 32) {
      wkj[tid >> 3][tid & 7] = Wk[(size_t)(a0 + (tid >> 3)) * cDU + j0 + (tid & 7)];
      __syncthreads();
#pragma unroll 8
      for (int aa = 0; aa < 32; ++aa) {
        float wq0 = Wq[(size_t)(a0 + aa) * cDM + tid * 2];
        float wq1 = Wq[(size_t)(a0 + aa) * cDM + tid * 2 + 1];
#pragma unroll
        for (int r = 0; r < 8; ++r) {
          acc[r][0] += wkj[aa][r] * wq0;
          acc[r][1] += wkj[aa][r] * wq1;
        }
      }
      __syncthreads();
    }
#pragma unroll
    for (int r = 0; r < 8; ++r) {
      wsf[F_A + (size_t)(j0 + r) * cDU + tid * 2] = acc[r][0];
      wsf[F_A + (size_t)(j0 + r) * cDU + tid * 2 + 1] = acc[r][1];
    }
    return;
  }
  const int gt = blockIdx.x * 256 + tid;
  const int nt = 1024 * 256;
  const int wv = tid >> 6, lane = tid & 63;
  const int gw = blockIdx.x * 4 + wv;
  const int nwv = 1024 * 4;

  for (int i = gt; i < cB * cDM; i += nt) wsf[F_M0 + i] = mem0[i];
  for (int i = gt; i < 512; i += nt) wsf[F_BAR + i] = 0.f;   // zero barrier counters

  if (use_ubf) {
    const int NU8 = cB * cT * cDU / 8;
    const float4* src = (const float4*)u;
    for (int c = gt; c < NU8; c += nt) {
      float4 f0 = src[(size_t)c * 2], f1 = src[(size_t)c * 2 + 1];
      u16x8 o;
      o[0] = f2bf(f0.x); o[1] = f2bf(f0.y); o[2] = f2bf(f0.z); o[3] = f2bf(f0.w);
      o[4] = f2bf(f1.x); o[5] = f2bf(f1.y); o[6] = f2bf(f1.z); o[7] = f2bf(f1.w);
      *(u16x8*)(ubf + (size_t)c * 8) = o;
    }
  }
  for (int row = gw; row < cB * cT; row += nwv) {
    float d0 = sf[(size_t)row * cDF + 8];
    float d1 = sf[(size_t)row * cDF + 9];
    float d2 = sf[(size_t)row * cDF + 10];
    float acc = 0.f;
#pragma unroll
    for (int i = 0; i < 4; ++i) {
      int a = lane * 4 + i;
      float h = d0 * w1[a * 3 + 0] + d1 * w1[a * 3 + 1] + d2 * w1[a * 3 + 2] + b1[a];
      float g = 0.5f * h * (1.0f + erff(h * 0.70710678118654752f));
      acc += g * w2[a];
    }
    float un = 0.f;
    const float4* ur = (const float4*)(u + (size_t)row * cDU);
#pragma unroll
    for (int m = 0; m < 2; ++m) { float4 x = ur[lane + m * 64]; un += dot4(x, x); }
    acc = wave_sum(acc);
    un = wave_sum(un);
    if (lane == 0) { wsf[F_SB + row] = acc + b2[0]; wsf[F_UN + row] = un; }
  }
}

// ==== k_main: whole 4-stage loop; 8 per-b block groups; fence-free coherent comms ====
__global__ __launch_bounds__(256, 4) void k_main(
    const float* __restrict__ u, const float* __restrict__ sim,
    const float* __restrict__ logt, const float* __restrict__ Wv,
    const float* __restrict__ W_ih, const float* __restrict__ b_ih,
    const float* __restrict__ W_hh, const float* __restrict__ b_hh,
    float* __restrict__ ws, u16* __restrict__ ubf, u8* __restrict__ sim8,
    float* __restrict__ out, int use_ubf, int use_s8) {
  __shared__ float lds[4104];          // [0..2175] ylds / [2048..4095] comb / [4096..] red
  float* red = lds + 4096;
  const int tid = threadIdx.x;
  const int wv = tid >> 6, lane = tid & 63;
  const int b = blockIdx.x & 7;         // same-b blocks land on one XCD (round-robin heur.)
  const int gb = blockIdx.x >> 3;       // block index within group
  const int G = gridDim.x >> 3;         // blocks per group
  const int gw = gb * 4 + wv;           // wave id within group
  const int GW = G * 4;                 // waves per group
  unsigned* cnt = (unsigned*)(ws + F_BAR) + (size_t)b * 64;   // 256B-spaced counters
  unsigned gen = 0;

  const float temp = fminf(fmaxf(expf(logt[0]), 0.1f), 10.0f);

  for (int stage = 0; stage < cL; ++stage) {
    float* mcur = ws + ((stage & 1) ? F_M1 : F_M0);
    float* mnxt = ws + ((stage & 1) ? F_M0 : F_M1);
    const int convert = (stage == 0 && use_s8) ? 1 : 0;

    // ---------- phase A: qk[b,:] = A @ mem[b,:]; zero c_raw[b,:] ----------
    for (int j = gw; j < cDM; j += GW) {
      const float4* ar = (const float4*)(ws + F_A + (size_t)j * cDM);
      float4 a0 = ar[lane * 2], a1 = ar[lane * 2 + 1];
      const float* mr = mcur + (size_t)b * cDM + lane * 8;
      float acc = a0.x * gload(mr + 0) + a0.y * gload(mr + 1) +
                  a0.z * gload(mr + 2) + a0.w * gload(mr + 3) +
                  a1.x * gload(mr + 4) + a1.y * gload(mr + 5) +
                  a1.z * gload(mr + 6) + a1.w * gload(mr + 7);
      acc = wave_sum(acc);
      if (lane == 0) gstore(ws + F_QK + b * cDU + j, acc);
    }
    for (int t = gb * 256 + tid; t < cDU; t += G * 256) gstore(ws + F_C + b * cDU + t, 0.f);
    ++gen; gbar(cnt, gen * G);

    // ---------- phase B: logits[b,:] ----------
    for (int s = gw; s < 512; s += GW) {
      const float* qkp = ws + F_QK + (size_t)b * cDU + lane * 8;
      float q[8];
#pragma unroll
      for (int e = 0; e < 8; ++e) q[e] = gload(qkp + e);
      float pv[32];
      if (stage > 0 && use_s8) {
        const float* pr = ws + F_PR + (size_t)b * cT;
#pragma unroll
        for (int m = 0; m < 2; ++m)
#pragma unroll
          for (int j = 0; j < 16; ++j) pv[m * 16 + j] = gload(pr + m * 1024 + lane * 16 + j);
      }
#pragma unroll
      for (int i = 0; i < 4; ++i) {
        int grow = b * cT + s * 4 + i;
        float acc;
        if (use_ubf) {
          u16x8 sv = *(const u16x8*)(ubf + (size_t)grow * cDU + lane * 8);
          acc = bf2f(sv[0]) * q[0] + bf2f(sv[1]) * q[1] + bf2f(sv[2]) * q[2] + bf2f(sv[3]) * q[3] +
                bf2f(sv[4]) * q[4] + bf2f(sv[5]) * q[5] + bf2f(sv[6]) * q[6] + bf2f(sv[7]) * q[7];
        } else {
          const float* ur = u + (size_t)grow * cDU + lane * 8;
          acc = 0.f;
#pragma unroll
          for (int e = 0; e < 8; ++e) acc += ur[e] * q[e];
        }
        acc *= (1.0f / cSCALE);
        if (stage > 0) {
          float sd = 0.f;
          if (use_s8) {
            const u8* sr = sim8 + (size_t)grow * cT;
            uint4 sq0 = *(const uint4*)(sr + lane * 16);
            uint4 sq1 = *(const uint4*)(sr + 1024 + lane * 16);
            dotu8p(sd, sq0.x, pv + 0);  dotu8p(sd, sq0.y, pv + 4);
            dotu8p(sd, sq0.z, pv + 8);  dotu8p(sd, sq0.w, pv + 12);
            dotu8p(sd, sq1.x, pv + 16); dotu8p(sd, sq1.y, pv + 20);
            dotu8p(sd, sq1.z, pv + 24); dotu8p(sd, sq1.w, pv + 28);
            sd *= (1.0f / 255.0f);
          } else {
            const float4* sr = (const float4*)(sim + (size_t)grow * cT);
            const float* pr = ws + F_PR + (size_t)b * cT;
#pragma unroll
            for (int m = 0; m < 8; ++m) {
              float4 sv = sr[lane + m * 64];
              int e0 = (lane + m * 64) * 4;
              sd += sv.x * gload(pr + e0) + sv.y * gload(pr + e0 + 1) +
                    sv.z * gload(pr + e0 + 2) + sv.w * gload(pr + e0 + 3);
            }
          }
          acc -= cGAMMA * sd;
        }
        acc = wave_sum(acc);
        if (lane == 0) gstore(ws + F_LG + grow, (acc + ws[F_SB + grow]) / temp);
      }
    }
    ++gen; gbar(cnt, gen * G);

    // ---------- phase C: softmax(logits[b,:]) + overlap = sim @ y1 (+stage-0 convert) --
    for (int ch = gb; ch < 128; ch += G) {
      float l[8];
      float mx = -INFINITY;
#pragma unroll
      for (int e = 0; e < 8; ++e) { l[e] = gload(ws + F_LG + b * cT + e * 256 + tid); mx = fmaxf(mx, l[e]); }
      mx = blk_max(mx, red, wv, lane);
      float sum = 0.f;
#pragma unroll
      for (int e = 0; e < 8; ++e) {
        float ev = expf(l[e] - mx);
        sum += ev;
        int sidx = e * 256 + tid;
        lds[sidx + (sidx >> 4)] = ev;
      }
      sum = blk_sum(sum, red, wv, lane);
      float invS = 1.f / sum;
      for (int r = 0; r < 4; ++r) {
        int row = b * cT + ch * 16 + wv * 4 + r;
        float acc = 0.f;
        if (use_s8 && !convert) {
          const u8* sr = sim8 + (size_t)row * cT;
#pragma unroll
          for (int m = 0; m < 2; ++m) {
            uint4 sq = *(const uint4*)(sr + m * 1024 + lane * 16);
            int s0 = m * 1024 + lane * 16;
#pragma unroll
            for (int k = 0; k < 4; ++k) {
              unsigned w = (&sq.x)[k];
              int si = s0 + k * 4;
              acc += (float)(w & 255u)         * lds[si + (si >> 4)] +
                     (float)((w >> 8) & 255u)  * lds[(si + 1) + ((si + 1) >> 4)] +
                     (float)((w >> 16) & 255u) * lds[(si + 2) + ((si + 2) >> 4)] +
                     (float)(w >> 24)          * lds[(si + 3) + ((si + 3) >> 4)];
            }
          }
          acc *= (1.0f / 255.0f);
        } else {
          const float4* sr = (const float4*)(sim + (size_t)row * cT);
#pragma unroll
          for (int m = 0; m < 2; ++m) {
            uint4 oq;
#pragma unroll
            for (int k = 0; k < 4; ++k) {
              float4 sv = sr[m * 256 + lane * 4 + k];
              int si = m * 1024 + lane * 16 + k * 4;
              acc += sv.x * lds[si + (si >> 4)] + sv.y * lds[(si + 1) + ((si + 1) >> 4)] +
                     sv.z * lds[(si + 2) + ((si + 2) >> 4)] + sv.w * lds[(si + 3) + ((si + 3) >> 4)];
              (&oq.x)[k] = pack4(sv.x, sv.y, sv.z, sv.w);
            }
            if (convert) {
              unsigned* dst = (unsigned*)(sim8 + (size_t)row * cT + m * 1024 + lane * 16);
#pragma unroll
              for (int k = 0; k < 4; ++k) gstore_u32(dst + k, (&oq.x)[k]);
            }
          }
        }
        acc = wave_sum(acc);
        if (lane == 0) gstore(ws + F_OV + row, acc * invS);
      }
    }
    ++gen; gbar(cnt, gen * G);

    // ---------- phase D: penalty + resoftmax + stats + centroid accumulate ----------
    for (int ch = gb; ch < 128; ch += G) {
      float o[8], l[8], yv8[8];
      float mo = -INFINITY;
#pragma unroll
      for (int e = 0; e < 8; ++e) { o[e] = gload(ws + F_OV + b * cT + e * 256 + tid); mo = fmaxf(mo, o[e]); }
      mo = fmaxf(blk_max(mo, red, wv, lane), cEPS);
      float ml = -INFINITY;
#pragma unroll
      for (int e = 0; e < 8; ++e) { l[e] = gload(ws + F_LG + b * cT + e * 256 + tid) - o[e] / mo; ml = fmaxf(ml, l[e]); }
      ml = blk_max(ml, red, wv, lane);
      float sum = 0.f;
#pragma unroll
      for (int e = 0; e < 8; ++e) { l[e] = expf(l[e] - ml); sum += l[e]; }
      sum = blk_sum(sum, red, wv, lane);
      float inv = 1.f / sum;
      float ysr_p = 0.f, wsq_p = 0.f;
#pragma unroll
      for (int e = 0; e < 8; ++e) {
        yv8[e] = l[e] * inv;
        lds[e * 256 + tid] = yv8[e];
        ysr_p += yv8[e];
        wsq_p += yv8[e] * ws[F_UN + b * cT + e * 256 + tid];
      }
      float ysr = blk_sum(ysr_p, red, wv, lane);
      float ysc = fmaxf(ysr, cEPS);
      float wsq = blk_sum(wsq_p, red, wv, lane);
      float ent_p = 0.f;
#pragma unroll
      for (int e = 0; e < 8; ++e) {
        float yn = yv8[e] / ysc;
        ent_p -= yn * logf(fmaxf(yn, cEPS));
      }
      float ent = blk_sum(ent_p, red, wv, lane);
      if (ch == 0) {
#pragma unroll
        for (int e = 0; e < 8; ++e) {
          int idx = b * cT + e * 256 + tid;
          gstore(ws + F_Y + idx, yv8[e]);
          if (stage == 0) gstore(ws + F_PR + idx, yv8[e]);
          else            gstore(ws + F_PR + idx, gload(ws + F_PR + idx) + yv8[e]);
        }
        if (tid == 0) {
          gstore(ws + F_SC + b * 8 + 0, ysc);
          gstore(ws + F_SC + b * 8 + 1, ysr / (float)cT);
          gstore(ws + F_SC + b * 8 + 2, ent);
          gstore(ws + F_SC + b * 8 + 3, wsq);
        }
      }
      float acc[8] = {};
      for (int i = 0; i < 4; ++i) {
        int r = ch * 16 + wv * 4 + i;
        float yvv = lds[r];
        int row = b * cT + r;
        if (use_ubf) {
          u16x8 s8v = *(const u16x8*)(ubf + (size_t)row * cDU + lane * 8);
#pragma unroll
          for (int e = 0; e < 8; ++e) acc[e] += yvv * bf2f(s8v[e]);
        } else {
          const float4* ur = (const float4*)(u + (size_t)row * cDU);
          float4 a0 = ur[lane * 2], a1 = ur[lane * 2 + 1];
          acc[0] += yvv * a0.x; acc[1] += yvv * a0.y; acc[2] += yvv * a0.z; acc[3] += yvv * a0.w;
          acc[4] += yvv * a1.x; acc[5] += yvv * a1.y; acc[6] += yvv * a1.z; acc[7] += yvv * a1.w;
        }
      }
      __syncthreads();
#pragma unroll
      for (int e = 0; e < 8; ++e) lds[2048 + wv * 512 + lane * 8 + e] = acc[e];
      __syncthreads();
      float s0 = lds[2048 + tid] + lds[2048 + 512 + tid] + lds[2048 + 1024 + tid] + lds[2048 + 1536 + tid];
      float s1 = lds[2048 + tid + 256] + lds[2048 + 512 + tid + 256] +
                 lds[2048 + 1024 + tid + 256] + lds[2048 + 1536 + tid + 256];
      atomicAdd(&ws[F_C + b * cDU + tid], s0);
      atomicAdd(&ws[F_C + b * cDU + tid + 256], s1);
      __syncthreads();
    }
    ++gen; gbar(cnt, gen * G);

    // ---------- phase E: z[b,:] = c_raw @ Wv^T ; spread partials ----------
    for (int j = gw; j < cDU; j += GW) {
      const float* cp = ws + F_C + (size_t)b * cDU + lane * 8;
      const float4* w4 = (const float4*)(Wv + (size_t)j * cDU);
      float4 w0 = w4[lane * 2], w1v = w4[lane * 2 + 1];
      float acc = w0.x * gload(cp + 0) + w0.y * gload(cp + 1) +
                  w0.z * gload(cp + 2) + w0.w * gload(cp + 3) +
                  w1v.x * gload(cp + 4) + w1v.y * gload(cp + 5) +
                  w1v.z * gload(cp + 6) + w1v.w * gload(cp + 7);
      acc = wave_sum(acc);
      if (lane == 0) gstore(ws + F_Z + b * cDU + j, acc);
    }
    for (int s = gw; s < 512; s += GW) {
      float ysc = gload(ws + F_SC + b * 8 + 0);
      float inv = 1.f / ysc;
      const float* cp = ws + F_C + (size_t)b * cDU + lane * 8;
      float cr[8];
#pragma unroll
      for (int e = 0; e < 8; ++e) cr[e] = gload(cp + e);
      float cx[8];
#pragma unroll
      for (int e = 0; e < 8; ++e) cx[e] = cr[e] * inv;
      float cd = 0.f, rd = 0.f;
#pragma unroll
      for (int e = 0; e < 8; ++e) { cd += cx[e] * cx[e]; rd += cr[e] * cr[e]; }
      float cen2 = wave_sum(cd);                  // lane0-valid
      if (s == 0) {
        float csq = wave_sum(rd);
        if (lane == 0) gstore(ws + F_SC + b * 8 + 6, csq);
      }
      float part = 0.f;
      for (int i = 0; i < 4; ++i) {
        int row = b * cT + s * 4 + i;
        float dot;
        if (use_ubf) {
          u16x8 sv = *(const u16x8*)(ubf + (size_t)row * cDU + lane * 8);
          dot = bf2f(sv[0]) * cx[0] + bf2f(sv[1]) * cx[1] + bf2f(sv[2]) * cx[2] + bf2f(sv[3]) * cx[3] +
                bf2f(sv[4]) * cx[4] + bf2f(sv[5]) * cx[5] + bf2f(sv[6]) * cx[6] + bf2f(sv[7]) * cx[7];
        } else {
          const float* ur = u + (size_t)row * cDU + lane * 8;
          dot = 0.f;
#pragma unroll
          for (int e = 0; e < 8; ++e) dot += ur[e] * cx[e];
        }
        dot = wave_sum(dot);
        if (lane == 0) {
          float d2 = ws[F_UN + row] - 2.f * dot + cen2;
          part += gload(ws + F_Y + row) * sqrtf(fmaxf(d2, 0.f));
        }
      }
      if (lane == 0) gstore(ws + F_SP + b * 512 + s, part);
    }
    ++gen; gbar(cnt, gen * G);

    // ---------- phase F: GRU gates + memory update + output ----------
    for (int t = gw; t < cDM; t += GW) {
      int i = t;
      const float* zp = ws + F_Z + (size_t)b * cDU + lane * 8;
      const float* mp = mcur + (size_t)b * cDM + lane * 8;
      float zv[8], mv[8];
#pragma unroll
      for (int e = 0; e < 8; ++e) { zv[e] = gload(zp + e); mv[e] = gload(mp + e); }
      float ysc = gload(ws + F_SC + b * 8 + 0);
      float sv_ = 0.f;
#pragma unroll
      for (int k2 = 0; k2 < 8; ++k2) sv_ += gload(ws + F_SP + b * 512 + lane * 8 + k2);
      float spr_raw = wave_sum(sv_);
      float aI[3], aH[3];
#pragma unroll
      for (int g = 0; g < 3; ++g) {
        size_t rrow = (size_t)(g * 512 + i);
        const float4* wI = (const float4*)(W_ih + rrow * 516);
        float4 wi0 = wI[lane * 2], wi1 = wI[lane * 2 + 1];
        float a = wi0.x * zv[0] + wi0.y * zv[1] + wi0.z * zv[2] + wi0.w * zv[3] +
                  wi1.x * zv[4] + wi1.y * zv[5] + wi1.z * zv[6] + wi1.w * zv[7];
        if (lane == 0) {
          float4 wt = wI[128];
          float cov = gload(ws + F_SC + b * 8 + 1), ent = gload(ws + F_SC + b * 8 + 2);
          float spr = spr_raw / ysc;
          float cmp = 2.f * (ysc * gload(ws + F_SC + b * 8 + 3) - gload(ws + F_SC + b * 8 + 6)) /
                      fmaxf(ysc * ysc, cEPS);
          a += cov * wt.x + ent * wt.y + spr * wt.z + cmp * wt.w;
        }
        aI[g] = wave_sum(a);
        const float4* wH = (const float4*)(W_hh + rrow * cDM);
        float4 wh0 = wH[lane * 2], wh1 = wH[lane * 2 + 1];
        float h = wh0.x * mv[0] + wh0.y * mv[1] + wh0.z * mv[2] + wh0.w * mv[3] +
                  wh1.x * mv[4] + wh1.y * mv[5] + wh1.z * mv[6] + wh1.w * mv[7];
        aH[g] = wave_sum(h);
      }
      if (lane == 0) {
        float gir = aI[0] + b_ih[i],        ghr = aH[0] + b_hh[i];
        float giz = aI[1] + b_ih[512 + i],  ghz = aH[1] + b_hh[512 + i];
        float gin = aI[2] + b_ih[1024 + i], ghn = aH[2] + b_hh[1024 + i];
        float rg = 1.f / (1.f + expf(-(gir + ghr)));
        float zg = 1.f / (1.f + expf(-(giz + ghz)));
        float ng = tanhf(gin + rg * ghn);
        float mold = gload(mcur + b * cDM + i);
        gstore(mnxt + b * cDM + i, (1.f - zg) * ng + zg * mold);
        out[(size_t)(b * cL + stage) * cDU + i] = gload(ws + F_Z + b * cDU + i);
      }
    }
    if (stage < cL - 1) { ++gen; gbar(cnt, gen * G); }
  }
}

extern "C" void kernel_launch(void* const* d_in, const int* in_sizes, int n_in,
                              void* d_out, int out_size, void* d_ws, size_t ws_size,
                              hipStream_t stream) {
  const float* u    = (const float*)d_in[0];
  const float* sf   = (const float*)d_in[1];
  const float* sim  = (const float*)d_in[2];
  const float* mem0 = (const float*)d_in[3];
  const float* Wq   = (const float*)d_in[4];
  const float* Wk   = (const float*)d_in[5];
  const float* Wv   = (const float*)d_in[6];
  const float* sbw1 = (const float*)d_in[7];
  const float* sbb1 = (const float*)d_in[8];
  const float* sbw2 = (const float*)d_in[9];
  const float* sbb2 = (const float*)d_in[10];
  const float* logt = (const float*)d_in[11];
  const float* W_ih = (const float*)d_in[12];
  const float* b_ih = (const float*)d_in[13];
  const float* W_hh = (const float*)d_in[14];
  const float* b_hh = (const float*)d_in[15];
  float* out = (float*)d_out;
  float* ws  = (float*)d_ws;
  u16* ubf  = (u16*)((char*)d_ws + U_OFFB);
  u8* sim8  = (u8*)((char*)d_ws + S8_OFFB);

  int use_ubf = (ws_size >= WS_NEED_U) ? 1 : 0;
  int use_s8  = (ws_size >= WS_NEED_ALL) ? 1 : 0;

  k_init<<<1088, 256, 0, stream>>>(u, sf, mem0, Wq, Wk, sbw1, sbb1, sbw2, sbb2,
                                   ws, ubf, use_ubf);

  // Cooperative launch only for the co-residency guarantee (spin barriers).
  static int nblk = 0;
  if (nblk == 0) {
    int occ = 0;
    if (hipOccupancyMaxActiveBlocksPerMultiprocessor(&occ, (const void*)k_main, 256, 0) != hipSuccess || occ <= 0)
      occ = 1;
    nblk = occ * 256;              // 256 CUs on MI355X
    if (nblk > 1024) nblk = 1024;
    if (nblk < 8) nblk = 8;
    nblk &= ~7;                    // multiple of 8 (one group per batch b)
  }
  void* kargs[] = {(void*)&u, (void*)&sim, (void*)&logt, (void*)&Wv,
                   (void*)&W_ih, (void*)&b_ih, (void*)&W_hh, (void*)&b_hh,
                   (void*)&ws, (void*)&ubf, (void*)&sim8, (void*)&out,
                   (void*)&use_ubf, (void*)&use_s8};
  hipLaunchCooperativeKernel((const void*)k_main, dim3(nblk), dim3(256), kargs, 0, stream);
}

// Round 4
// 494.726 us; speedup vs baseline: 3.7309x; 2.3032x over previous
//
#include <hip/hip_runtime.h>
#include <math.h>

constexpr int cB = 8, cT = 2048, cDU = 512, cDM = 512, cDA = 256, cDF = 12, cL = 4;
constexpr float cEPS = 1e-6f;
constexpr float cSCALE = 16.0f;   // sqrt(DA)
constexpr float cGAMMA = 1.0f;

typedef unsigned short u16;
typedef unsigned char u8;
typedef u16 u16x8 __attribute__((ext_vector_type(8)));

// ---------------- workspace layout (float offsets) ----------------
constexpr size_t F_SB = 0;                 // sbias  B*T
constexpr size_t F_UN = F_SB + 16384;      // unorm2 B*T
constexpr size_t F_LG = F_UN + 16384;      // logits B*T
constexpr size_t F_Y  = F_LG + 16384;      // y (final, per stage) B*T
constexpr size_t F_PR = F_Y  + 16384;      // prev   B*T
constexpr size_t F_OV = F_PR + 16384;      // overlap B*T
constexpr size_t F_SP = F_OV + 16384;      // spread partials B*32
constexpr size_t F_QK = F_SP + 256;        // qk  B*DU
constexpr size_t F_M0 = F_QK + 4096;       // memory buf 0
constexpr size_t F_M1 = F_M0 + 4096;       // memory buf 1
constexpr size_t F_C  = F_M1 + 4096;       // c_raw B*DU
constexpr size_t F_Z  = F_C  + 4096;       // z B*DU
constexpr size_t F_SC = F_Z  + 4096;       // scalars B*8
constexpr size_t F_A  = F_SC + 64;         // A = Wk^T @ Wq, 512x512
constexpr size_t F_END = F_A + 262144;
constexpr size_t U_OFFB   = F_END * 4;                       // bf16 u
constexpr size_t U_BYTES  = (size_t)cB * cT * cDU * 2;
constexpr size_t S8_OFFB  = U_OFFB + U_BYTES;                // u8 sim
constexpr size_t S8_BYTES = (size_t)cB * cT * cT;
constexpr size_t WS_NEED_U   = S8_OFFB;
constexpr size_t WS_NEED_ALL = S8_OFFB + S8_BYTES;
// scal: 0 ysum_clamped, 1 coverage, 2 entropy, 3 wsq, 6 csq

__device__ __forceinline__ float wave_sum(float v) {
#pragma unroll
  for (int o = 32; o; o >>= 1) v += __shfl_down(v, o);
  return v;   // valid on lane 0
}
__device__ __forceinline__ u16 f2bf(float f) {
  unsigned u = __float_as_uint(f);
  return (u16)((u + 0x7fffu + ((u >> 16) & 1u)) >> 16);
}
__device__ __forceinline__ float bf2f(u16 h) { return __uint_as_float(((unsigned)h) << 16); }
__device__ __forceinline__ float dot4(float4 a, float4 b) {
  return a.x * b.x + a.y * b.y + a.z * b.z + a.w * b.w;
}
__device__ __forceinline__ unsigned pack4(float a, float b, float c, float d) {
  unsigned b0 = (unsigned)(a * 255.f + 0.5f);
  unsigned b1 = (unsigned)(b * 255.f + 0.5f);
  unsigned b2 = (unsigned)(c * 255.f + 0.5f);
  unsigned b3 = (unsigned)(d * 255.f + 0.5f);
  return b0 | (b1 << 8) | (b2 << 16) | (b3 << 24);
}
__device__ __forceinline__ void dotu8(float& sd, unsigned w, float4 p) {
  sd += (float)(w & 255u) * p.x + (float)((w >> 8) & 255u) * p.y +
        (float)((w >> 16) & 255u) * p.z + (float)(w >> 24) * p.w;
}

// ==== k_init: blocks 0..1023 mem0 copy + u->bf16 + sbias/unorm2; 1024..1087 A=Wk^T@Wq ==
__global__ __launch_bounds__(256) void k_init(
    const float* __restrict__ u, const float* __restrict__ sf,
    const float* __restrict__ mem0,
    const float* __restrict__ Wq, const float* __restrict__ Wk,
    const float* __restrict__ w1, const float* __restrict__ b1,
    const float* __restrict__ w2, const float* __restrict__ b2,
    float* __restrict__ wsf, u16* __restrict__ ubf, int use_ubf) {
  const int tid = threadIdx.x;
  if (blockIdx.x >= 1024) {
    // A[j,i] = sum_a Wk[a,j] * Wq[a,i];  block handles 8 j rows
    __shared__ float wkj[32][8];
    int j0 = (blockIdx.x - 1024) * 8;
    float acc[8][2] = {};
    for (int a0 = 0; a0 < cDA; a0 += 32) {
      wkj[tid >> 3][tid & 7] = Wk[(size_t)(a0 + (tid >> 3)) * cDU + j0 + (tid & 7)];
      __syncthreads();
#pragma unroll 8
      for (int aa = 0; aa < 32; ++aa) {
        float wq0 = Wq[(size_t)(a0 + aa) * cDM + tid * 2];
        float wq1 = Wq[(size_t)(a0 + aa) * cDM + tid * 2 + 1];
#pragma unroll
        for (int r = 0; r < 8; ++r) {
          acc[r][0] += wkj[aa][r] * wq0;
          acc[r][1] += wkj[aa][r] * wq1;
        }
      }
      __syncthreads();
    }
#pragma unroll
    for (int r = 0; r < 8; ++r) {
      wsf[F_A + (size_t)(j0 + r) * cDU + tid * 2] = acc[r][0];
      wsf[F_A + (size_t)(j0 + r) * cDU + tid * 2 + 1] = acc[r][1];
    }
    return;
  }
  const int gt = blockIdx.x * 256 + tid;
  const int nt = 1024 * 256;
  const int wv = tid >> 6, lane = tid & 63;
  const int gw = blockIdx.x * 4 + wv;
  const int nw = 1024 * 4;

  for (int i = gt; i < cB * cDM; i += nt) wsf[F_M0 + i] = mem0[i];

  if (use_ubf) {
    const int NU8 = cB * cT * cDU / 8;
    const float4* src = (const float4*)u;
    for (int c = gt; c < NU8; c += nt) {
      float4 f0 = src[(size_t)c * 2], f1 = src[(size_t)c * 2 + 1];
      u16x8 o;
      o[0] = f2bf(f0.x); o[1] = f2bf(f0.y); o[2] = f2bf(f0.z); o[3] = f2bf(f0.w);
      o[4] = f2bf(f1.x); o[5] = f2bf(f1.y); o[6] = f2bf(f1.z); o[7] = f2bf(f1.w);
      *(u16x8*)(ubf + (size_t)c * 8) = o;
    }
  }
  for (int row = gw; row < cB * cT; row += nw) {
    float d0 = sf[(size_t)row * cDF + 8];
    float d1 = sf[(size_t)row * cDF + 9];
    float d2 = sf[(size_t)row * cDF + 10];
    float acc = 0.f;
#pragma unroll
    for (int i = 0; i < 4; ++i) {
      int a = lane * 4 + i;
      float h = d0 * w1[a * 3 + 0] + d1 * w1[a * 3 + 1] + d2 * w1[a * 3 + 2] + b1[a];
      float g = 0.5f * h * (1.0f + erff(h * 0.70710678118654752f));
      acc += g * w2[a];
    }
    float un = 0.f;
    const float4* ur = (const float4*)(u + (size_t)row * cDU);
#pragma unroll
    for (int m = 0; m < 2; ++m) { float4 x = ur[lane + m * 64]; un += dot4(x, x); }
    acc = wave_sum(acc);
    un = wave_sum(un);
    if (lane == 0) { wsf[F_SB + row] = acc + b2[0]; wsf[F_UN + row] = un; }
  }
}

// =============== k_qk: qk[b,:] = A @ mem[b,:]; zero c_raw.  b = blockIdx&7 (XCD affin.)
__global__ __launch_bounds__(256) void k_qk(const float* __restrict__ A,
                                            const float* __restrict__ mem,
                                            float* __restrict__ qk,
                                            float* __restrict__ c_raw) {
  int wv = threadIdx.x >> 6, lane = threadIdx.x & 63;
  int b = blockIdx.x & 7;
  int j = (blockIdx.x >> 3) * 4 + wv;        // 0..511
  const float4* ar = (const float4*)(A + (size_t)j * cDM);
  const float4* mr = (const float4*)(mem + (size_t)b * cDM);
  float acc = dot4(ar[lane * 2], mr[lane * 2]) + dot4(ar[lane * 2 + 1], mr[lane * 2 + 1]);
  acc = wave_sum(acc);
  if (lane == 0) qk[b * cDU + j] = acc;
  int gt = blockIdx.x * 256 + threadIdx.x;
  if (gt < cB * cDU) c_raw[gt] = 0.f;
}

// =============== k_scores: logits = (u.qk/SCALE + sbias - g*sim@prev)/temp =============
// b = blockIdx&7 so all of b's rows land on one XCD (sim8[b]+ubf[b] L2-resident
// across the stage's dispatch sequence).
__global__ __launch_bounds__(256) void k_scores(
    const u16* __restrict__ ubf, const float* __restrict__ uf,
    const float* __restrict__ qk, const float* __restrict__ sbias,
    const u8* __restrict__ sim8, const float* __restrict__ simf,
    const float* __restrict__ prev, const float* __restrict__ log_temp,
    float gamma, int use_ubf, int use_s8, float* __restrict__ logits) {
  int wv = threadIdx.x >> 6;
  int lane = threadIdx.x & 63;
  int b = blockIdx.x & 7;
  int t = (blockIdx.x >> 3) * 4 + wv;        // 0..2047
  int grow = b * cT + t;
  const float4* qk4 = (const float4*)(qk + (size_t)b * cDU);
  float4 q0 = qk4[lane * 2], q1 = qk4[lane * 2 + 1];
  float acc;
  if (use_ubf) {
    u16x8 s = *(const u16x8*)(ubf + (size_t)grow * cDU + lane * 8);
    acc = bf2f(s[0]) * q0.x + bf2f(s[1]) * q0.y + bf2f(s[2]) * q0.z + bf2f(s[3]) * q0.w +
          bf2f(s[4]) * q1.x + bf2f(s[5]) * q1.y + bf2f(s[6]) * q1.z + bf2f(s[7]) * q1.w;
  } else {
    const float4* ur = (const float4*)(uf + (size_t)grow * cDU);
    acc = dot4(ur[lane * 2], q0) + dot4(ur[lane * 2 + 1], q1);
  }
  acc *= (1.0f / cSCALE);
  if (gamma != 0.0f) {
    float sd = 0.f;
    const float4* pr4 = (const float4*)(prev + (size_t)b * cT);
    if (use_s8) {
#pragma unroll
      for (int m = 0; m < 2; ++m) {
        uint4 sq = *(const uint4*)(sim8 + (size_t)grow * cT + m * 1024 + lane * 16);
        const float4* pb = pr4 + m * 256 + lane * 4;
        dotu8(sd, sq.x, pb[0]); dotu8(sd, sq.y, pb[1]);
        dotu8(sd, sq.z, pb[2]); dotu8(sd, sq.w, pb[3]);
      }
      sd *= (1.0f / 255.0f);
    } else {
      const float4* sr = (const float4*)(simf + (size_t)grow * cT);
#pragma unroll
      for (int m = 0; m < 8; ++m) sd += dot4(sr[lane + m * 64], pr4[lane + m * 64]);
    }
    acc -= gamma * sd;
  }
  acc = wave_sum(acc);
  if (lane == 0) {
    float temp = fminf(fmaxf(expf(log_temp[0]), 0.1f), 10.0f);
    logits[grow] = (acc + sbias[grow]) / temp;
  }
}

// =============== k_overlap: softmax(logits) once per 16 rows + overlap = sim @ y1 =====
// grid 1024, block 256; b = blockIdx&7, ch = blockIdx>>3 (0..127); 16 rows per block.
__global__ __launch_bounds__(256) void k_overlap(
    const u8* __restrict__ sim8c, u8* __restrict__ sim8w,
    const float* __restrict__ simf,
    const float* __restrict__ logits, int use_s8, int convert,
    float* __restrict__ overlap) {
  __shared__ float ylds[2176];   // padded: a = s + (s>>4)
  __shared__ float red[256];
  const int tid = threadIdx.x;
  const int wv = tid >> 6, lane = tid & 63;
  const int b = blockIdx.x & 7;
  const int ch = blockIdx.x >> 3;              // 0..127
  float l[8];
  float mx = -INFINITY;
#pragma unroll
  for (int e = 0; e < 8; ++e) { l[e] = logits[b * cT + e * 256 + tid]; mx = fmaxf(mx, l[e]); }
  red[tid] = mx; __syncthreads();
  for (int s2 = 128; s2; s2 >>= 1) { if (tid < s2) red[tid] = fmaxf(red[tid], red[tid + s2]); __syncthreads(); }
  mx = red[0]; __syncthreads();
  float sum = 0.f;
#pragma unroll
  for (int e = 0; e < 8; ++e) {
    float ev = expf(l[e] - mx);
    sum += ev;
    int s = e * 256 + tid;
    ylds[s + (s >> 4)] = ev;
  }
  red[tid] = sum; __syncthreads();
  for (int s2 = 128; s2; s2 >>= 1) { if (tid < s2) red[tid] += red[tid + s2]; __syncthreads(); }
  float invS = 1.f / red[0];
  __syncthreads();
  for (int r = 0; r < 4; ++r) {
    int row = b * cT + ch * 16 + wv * 4 + r;
    float acc = 0.f;
    if (use_s8 && !convert) {
#pragma unroll
      for (int m = 0; m < 2; ++m) {
        uint4 sq = *(const uint4*)(sim8c + (size_t)row * cT + m * 1024 + lane * 16);
        int s0 = m * 1024 + lane * 16;
#pragma unroll
        for (int k = 0; k < 4; ++k) {
          unsigned w = (&sq.x)[k];
          int s = s0 + k * 4;
          acc += (float)(w & 255u)         * ylds[s + (s >> 4)] +
                 (float)((w >> 8) & 255u)  * ylds[(s + 1) + ((s + 1) >> 4)] +
                 (float)((w >> 16) & 255u) * ylds[(s + 2) + ((s + 2) >> 4)] +
                 (float)(w >> 24)          * ylds[(s + 3) + ((s + 3) >> 4)];
        }
      }
      acc *= (1.0f / 255.0f);
    } else {
#pragma unroll
      for (int m = 0; m < 2; ++m) {
        const float4* sr = (const float4*)(simf + (size_t)row * cT + m * 1024 + lane * 16);
        uint4 oq;
#pragma unroll
        for (int k = 0; k < 4; ++k) {
          float4 sv = sr[k];
          int s = m * 1024 + lane * 16 + k * 4;
          acc += sv.x * ylds[s + (s >> 4)] + sv.y * ylds[(s + 1) + ((s + 1) >> 4)] +
                 sv.z * ylds[(s + 2) + ((s + 2) >> 4)] + sv.w * ylds[(s + 3) + ((s + 3) >> 4)];
          (&oq.x)[k] = pack4(sv.x, sv.y, sv.z, sv.w);
        }
        if (convert)
          *(uint4*)(sim8w + (size_t)row * cT + m * 1024 + lane * 16) = oq;
      }
    }
    acc = wave_sum(acc);
    if (lane == 0) overlap[row] = acc * invS;
  }
}

// =============== k_statcen: penalty+resoftmax+stats + centroid chunk accum =============
// grid 256 linear: b = blockIdx&7, ch = blockIdx>>3 (0..31); 64 rows per chunk.
__global__ __launch_bounds__(256) void k_statcen(
    const float* __restrict__ overlap, const float* __restrict__ logits,
    const float* __restrict__ unorm2,
    const u16* __restrict__ ubf, const float* __restrict__ uf, int use_ubf,
    float* __restrict__ y, float* __restrict__ prev,
    float* __restrict__ scal, float* __restrict__ c_raw, int first_stage) {
  __shared__ float ylds[2048];
  __shared__ float comb[2048];
  __shared__ float red[256];
  const int tid = threadIdx.x;
  const int wv = tid >> 6, lane = tid & 63;
  const int b = blockIdx.x & 7;
  const int ch = blockIdx.x >> 3;              // 0..31
  float o[8], l[8], yv[8];
  float mo = -INFINITY;
#pragma unroll
  for (int e = 0; e < 8; ++e) { o[e] = overlap[b * cT + e * 256 + tid]; mo = fmaxf(mo, o[e]); }
  red[tid] = mo; __syncthreads();
  for (int s2 = 128; s2; s2 >>= 1) { if (tid < s2) red[tid] = fmaxf(red[tid], red[tid + s2]); __syncthreads(); }
  mo = fmaxf(red[0], cEPS); __syncthreads();
  float ml = -INFINITY;
#pragma unroll
  for (int e = 0; e < 8; ++e) { l[e] = logits[b * cT + e * 256 + tid] - o[e] / mo; ml = fmaxf(ml, l[e]); }
  red[tid] = ml; __syncthreads();
  for (int s2 = 128; s2; s2 >>= 1) { if (tid < s2) red[tid] = fmaxf(red[tid], red[tid + s2]); __syncthreads(); }
  ml = red[0]; __syncthreads();
  float sum = 0.f;
#pragma unroll
  for (int e = 0; e < 8; ++e) { l[e] = expf(l[e] - ml); sum += l[e]; }
  red[tid] = sum; __syncthreads();
  for (int s2 = 128; s2; s2 >>= 1) { if (tid < s2) red[tid] += red[tid + s2]; __syncthreads(); }
  float inv = 1.f / red[0]; __syncthreads();
  float ysr_p = 0.f, wsq_p = 0.f;
#pragma unroll
  for (int e = 0; e < 8; ++e) {
    yv[e] = l[e] * inv;
    ylds[e * 256 + tid] = yv[e];
    ysr_p += yv[e];
    wsq_p += yv[e] * unorm2[b * cT + e * 256 + tid];
  }
  red[tid] = ysr_p; __syncthreads();
  for (int s2 = 128; s2; s2 >>= 1) { if (tid < s2) red[tid] += red[tid + s2]; __syncthreads(); }
  float ysr = red[0]; __syncthreads();
  float ysc = fmaxf(ysr, cEPS);
  red[tid] = wsq_p; __syncthreads();
  for (int s2 = 128; s2; s2 >>= 1) { if (tid < s2) red[tid] += red[tid + s2]; __syncthreads(); }
  float wsq = red[0]; __syncthreads();
  float ent_p = 0.f;
#pragma unroll
  for (int e = 0; e < 8; ++e) {
    float yn = yv[e] / ysc;
    ent_p -= yn * logf(fmaxf(yn, cEPS));
  }
  red[tid] = ent_p; __syncthreads();
  for (int s2 = 128; s2; s2 >>= 1) { if (tid < s2) red[tid] += red[tid + s2]; __syncthreads(); }
  float ent = red[0]; __syncthreads();
  if (ch == 0) {
#pragma unroll
    for (int e = 0; e < 8; ++e) {
      int idx = b * cT + e * 256 + tid;
      y[idx] = yv[e];
      if (first_stage) prev[idx] = yv[e]; else prev[idx] += yv[e];
    }
    if (tid == 0) {
      scal[b * 8 + 0] = ysc;
      scal[b * 8 + 1] = ysr / (float)cT;
      scal[b * 8 + 2] = ent;
      scal[b * 8 + 3] = wsq;
    }
  }
  float acc[8] = {};
  for (int i = 0; i < 16; ++i) {
    int r = ch * 64 + wv * 16 + i;
    float yvv = ylds[r];
    int row = b * cT + r;
    if (use_ubf) {
      u16x8 s8 = *(const u16x8*)(ubf + (size_t)row * cDU + lane * 8);
#pragma unroll
      for (int e = 0; e < 8; ++e) acc[e] += yvv * bf2f(s8[e]);
    } else {
      const float4* ur = (const float4*)(uf + (size_t)row * cDU);
      float4 a0 = ur[lane * 2], a1 = ur[lane * 2 + 1];
      acc[0] += yvv * a0.x; acc[1] += yvv * a0.y; acc[2] += yvv * a0.z; acc[3] += yvv * a0.w;
      acc[4] += yvv * a1.x; acc[5] += yvv * a1.y; acc[6] += yvv * a1.z; acc[7] += yvv * a1.w;
    }
  }
  __syncthreads();
#pragma unroll
  for (int e = 0; e < 8; ++e) comb[wv * 512 + lane * 8 + e] = acc[e];
  __syncthreads();
  float s0 = comb[tid] + comb[512 + tid] + comb[1024 + tid] + comb[1536 + tid];
  float s1 = comb[tid + 256] + comb[512 + tid + 256] + comb[1024 + tid + 256] + comb[1536 + tid + 256];
  atomicAdd(&c_raw[b * cDU + tid], s0);
  atomicAdd(&c_raw[b * cDU + tid + 256], s1);
}

// =============== k_zyd: blocks 0..1023 -> z = c_raw@Wv^T ; 1024..1279 -> spread ======
// z-part: b = blk&7, j = (blk>>3)*4+wv.  spread: b = unit&7, tc = unit>>3.
__global__ __launch_bounds__(256) void k_zyd(
    const float* __restrict__ c_raw, const float* __restrict__ Wv,
    const u16* __restrict__ ubf, const float* __restrict__ uf, int use_ubf,
    const float* __restrict__ unorm2, const float* __restrict__ y,
    float* __restrict__ z, float* __restrict__ scal, float* __restrict__ sprp) {
  __shared__ float s4[4];
  int wv = threadIdx.x >> 6, lane = threadIdx.x & 63;
  if (blockIdx.x < 1024) {
    int b = blockIdx.x & 7;
    int j = (blockIdx.x >> 3) * 4 + wv;      // 0..511
    const float4* c4 = (const float4*)(c_raw + (size_t)b * cDU);
    const float4* w4 = (const float4*)(Wv + (size_t)j * cDU);
    float acc = dot4(c4[lane * 2], w4[lane * 2]) + dot4(c4[lane * 2 + 1], w4[lane * 2 + 1]);
    acc = wave_sum(acc);
    if (lane == 0) z[b * cDU + j] = acc;
    return;
  }
  int unit = blockIdx.x - 1024;   // 0..255
  int b = unit & 7, tc = unit >> 3;          // tc 0..31
  float ysc = scal[b * 8 + 0];
  float inv = 1.f / ysc;
  const float4* c4 = (const float4*)(c_raw + (size_t)b * cDU);
  float4 cr0 = c4[lane * 2], cr1 = c4[lane * 2 + 1];
  float4 cx0, cx1;
  cx0.x = cr0.x * inv; cx0.y = cr0.y * inv; cx0.z = cr0.z * inv; cx0.w = cr0.w * inv;
  cx1.x = cr1.x * inv; cx1.y = cr1.y * inv; cx1.z = cr1.z * inv; cx1.w = cr1.w * inv;
  float cen2 = wave_sum(dot4(cx0, cx0) + dot4(cx1, cx1));     // lane0-valid
  if (tc == 0 && wv == 0) {
    float csq = wave_sum(dot4(cr0, cr0) + dot4(cr1, cr1));
    if (lane == 0) scal[b * 8 + 6] = csq;
  }
  float part = 0.f;
  for (int i = 0; i < 16; ++i) {
    int row = b * cT + tc * 64 + wv * 16 + i;
    float dot;
    if (use_ubf) {
      u16x8 s = *(const u16x8*)(ubf + (size_t)row * cDU + lane * 8);
      dot = bf2f(s[0]) * cx0.x + bf2f(s[1]) * cx0.y + bf2f(s[2]) * cx0.z + bf2f(s[3]) * cx0.w +
            bf2f(s[4]) * cx1.x + bf2f(s[5]) * cx1.y + bf2f(s[6]) * cx1.z + bf2f(s[7]) * cx1.w;
    } else {
      const float4* ur = (const float4*)(uf + (size_t)row * cDU);
      dot = dot4(ur[lane * 2], cx0) + dot4(ur[lane * 2 + 1], cx1);
    }
    dot = wave_sum(dot);
    if (lane == 0) {
      float d2 = unorm2[row] - 2.f * dot + cen2;
      part += y[row] * sqrtf(fmaxf(d2, 0.f));
    }
  }
  if (lane == 0) s4[wv] = part;
  __syncthreads();
  if (threadIdx.x == 0) sprp[b * 32 + tc] = s4[0] + s4[1] + s4[2] + s4[3];
}

// =============== k_gru: gates + memory update + output (wave per (b,i)) ==============
// keep original mapping: blocks ±128 share i-range -> same XCD mod 8 -> W reuse.
__global__ __launch_bounds__(256) void k_gru(const float* __restrict__ z,
                                             const float* __restrict__ scal,
                                             const float* __restrict__ sprp,
                                             const float* __restrict__ memin,
                                             float* __restrict__ memout,
                                             const float* __restrict__ W_ih,
                                             const float* __restrict__ b_ih,
                                             const float* __restrict__ W_hh,
                                             const float* __restrict__ b_hh,
                                             float* __restrict__ out, int stage) {
  int wid = blockIdx.x * 4 + (threadIdx.x >> 6);
  int lane = threadIdx.x & 63;
  int b = wid >> 9, i = wid & 511;
  const float4* xz = (const float4*)(z + (size_t)b * cDU);
  const float4* xm = (const float4*)(memin + (size_t)b * cDM);
  float4 z0 = xz[lane * 2], z1 = xz[lane * 2 + 1];
  float4 m0 = xm[lane * 2], m1 = xm[lane * 2 + 1];
  float ysc = scal[b * 8 + 0];
  float sv = (lane < 32) ? sprp[b * 32 + lane] : 0.f;
  float spr_raw = wave_sum(sv);
  float aI[3], aH[3];
#pragma unroll
  for (int g = 0; g < 3; ++g) {
    size_t row = (size_t)(g * 512 + i);
    const float4* wI = (const float4*)(W_ih + row * 516);
    float a = dot4(z0, wI[lane * 2]) + dot4(z1, wI[lane * 2 + 1]);
    if (lane == 0) {
      float4 wt = wI[128];
      float cov = scal[b * 8 + 1], ent = scal[b * 8 + 2];
      float spr = spr_raw / ysc;
      float cmp = 2.f * (ysc * scal[b * 8 + 3] - scal[b * 8 + 6]) / fmaxf(ysc * ysc, cEPS);
      a += cov * wt.x + ent * wt.y + spr * wt.z + cmp * wt.w;
    }
    aI[g] = wave_sum(a);
    const float4* wH = (const float4*)(W_hh + row * cDM);
    float h = dot4(m0, wH[lane * 2]) + dot4(m1, wH[lane * 2 + 1]);
    aH[g] = wave_sum(h);
  }
  if (lane == 0) {
    float gir = aI[0] + b_ih[i],        ghr = aH[0] + b_hh[i];
    float giz = aI[1] + b_ih[512 + i],  ghz = aH[1] + b_hh[512 + i];
    float gin = aI[2] + b_ih[1024 + i], ghn = aH[2] + b_hh[1024 + i];
    float rg = 1.f / (1.f + expf(-(gir + ghr)));
    float zg = 1.f / (1.f + expf(-(giz + ghz)));
    float ng = tanhf(gin + rg * ghn);
    float mold = memin[b * cDM + i];
    memout[b * cDM + i] = (1.f - zg) * ng + zg * mold;
    out[(size_t)(b * cL + stage) * cDU + i] = z[b * cDU + i];
  }
}

extern "C" void kernel_launch(void* const* d_in, const int* in_sizes, int n_in,
                              void* d_out, int out_size, void* d_ws, size_t ws_size,
                              hipStream_t stream) {
  const float* u    = (const float*)d_in[0];
  const float* sf   = (const float*)d_in[1];
  const float* sim  = (const float*)d_in[2];
  const float* mem0 = (const float*)d_in[3];
  const float* Wq   = (const float*)d_in[4];
  const float* Wk   = (const float*)d_in[5];
  const float* Wv   = (const float*)d_in[6];
  const float* sbw1 = (const float*)d_in[7];
  const float* sbb1 = (const float*)d_in[8];
  const float* sbw2 = (const float*)d_in[9];
  const float* sbb2 = (const float*)d_in[10];
  const float* logt = (const float*)d_in[11];
  const float* W_ih = (const float*)d_in[12];
  const float* b_ih = (const float*)d_in[13];
  const float* W_hh = (const float*)d_in[14];
  const float* b_hh = (const float*)d_in[15];
  float* out = (float*)d_out;
  float* ws  = (float*)d_ws;
  u16* ubf  = (u16*)((char*)d_ws + U_OFFB);
  u8* sim8  = (u8*)((char*)d_ws + S8_OFFB);

  const int use_ubf = (ws_size >= WS_NEED_U) ? 1 : 0;
  const int use_s8  = (ws_size >= WS_NEED_ALL) ? 1 : 0;

  k_init<<<1088, 256, 0, stream>>>(u, sf, mem0, Wq, Wk, sbw1, sbb1, sbw2, sbb2,
                                   ws, ubf, use_ubf);

  for (int stage = 0; stage < cL; ++stage) {
    float* mcur = ws + ((stage & 1) ? F_M1 : F_M0);
    float* mnxt = ws + ((stage & 1) ? F_M0 : F_M1);
    k_qk<<<1024, 256, 0, stream>>>(ws + F_A, mcur, ws + F_QK, ws + F_C);
    k_scores<<<4096, 256, 0, stream>>>(ubf, u, ws + F_QK, ws + F_SB, sim8, sim,
                                       ws + F_PR, logt, stage == 0 ? 0.0f : cGAMMA,
                                       use_ubf, use_s8, ws + F_LG);
    k_overlap<<<1024, 256, 0, stream>>>(sim8, sim8, sim, ws + F_LG, use_s8,
                                        (stage == 0 && use_s8) ? 1 : 0, ws + F_OV);
    k_statcen<<<256, 256, 0, stream>>>(ws + F_OV, ws + F_LG, ws + F_UN,
                                       ubf, u, use_ubf,
                                       ws + F_Y, ws + F_PR, ws + F_SC, ws + F_C,
                                       stage == 0 ? 1 : 0);
    k_zyd<<<1280, 256, 0, stream>>>(ws + F_C, Wv, ubf, u, use_ubf,
                                    ws + F_UN, ws + F_Y, ws + F_Z, ws + F_SC, ws + F_SP);
    k_gru<<<1024, 256, 0, stream>>>(ws + F_Z, ws + F_SC, ws + F_SP, mcur, mnxt,
                                    W_ih, b_ih, W_hh, b_hh, out, stage);
  }
}

// Round 5
// 464.017 us; speedup vs baseline: 3.9779x; 1.0662x over previous
//
#include <hip/hip_runtime.h>
#include <math.h>

constexpr int cB = 8, cT = 2048, cDU = 512, cDM = 512, cDA = 256, cDF = 12, cL = 4;
constexpr float cEPS = 1e-6f;
constexpr float cSCALE = 16.0f;   // sqrt(DA)
constexpr float cGAMMA = 1.0f;

typedef unsigned short u16;
typedef unsigned char u8;
typedef u16 u16x8 __attribute__((ext_vector_type(8)));

// ---------------- workspace layout (float offsets) ----------------
constexpr size_t F_SB = 0;                 // sbias  B*T
constexpr size_t F_UN = F_SB + 16384;      // unorm2 B*T
constexpr size_t F_LG = F_UN + 16384;      // logits B*T
constexpr size_t F_Y  = F_LG + 16384;      // y (final, per stage) B*T
constexpr size_t F_PR = F_Y  + 16384;      // prev   B*T
constexpr size_t F_OV = F_PR + 16384;      // overlap B*T
constexpr size_t F_SP = F_OV + 16384;      // spread partials B*128
constexpr size_t F_QK = F_SP + 1024;       // qk  B*DU
constexpr size_t F_M0 = F_QK + 4096;       // memory buf 0
constexpr size_t F_M1 = F_M0 + 4096;       // memory buf 1
constexpr size_t F_C  = F_M1 + 4096;       // c_raw B*DU
constexpr size_t F_Z  = F_C  + 4096;       // z B*DU
constexpr size_t F_SC = F_Z  + 4096;       // scalars B*8
constexpr size_t F_A  = F_SC + 64;         // A = Wk^T @ Wq, 512x512
constexpr size_t F_END = F_A + 262144;
constexpr size_t U_OFFB   = F_END * 4;                       // bf16 u
constexpr size_t U_BYTES  = (size_t)cB * cT * cDU * 2;
constexpr size_t S8_OFFB  = U_OFFB + U_BYTES;                // u8 sim
constexpr size_t S8_BYTES = (size_t)cB * cT * cT;
constexpr size_t WS_NEED_U   = S8_OFFB;
constexpr size_t WS_NEED_ALL = S8_OFFB + S8_BYTES;
// scal: 0 ysum_clamped, 1 coverage, 2 entropy, 3 wsq, 6 csq

__device__ __forceinline__ float wave_sum(float v) {
#pragma unroll
  for (int o = 32; o; o >>= 1) v += __shfl_down(v, o);
  return v;   // valid on lane 0
}
__device__ __forceinline__ u16 f2bf(float f) {
  unsigned u = __float_as_uint(f);
  return (u16)((u + 0x7fffu + ((u >> 16) & 1u)) >> 16);
}
__device__ __forceinline__ float bf2f(u16 h) { return __uint_as_float(((unsigned)h) << 16); }
__device__ __forceinline__ float dot4(float4 a, float4 b) {
  return a.x * b.x + a.y * b.y + a.z * b.z + a.w * b.w;
}
__device__ __forceinline__ unsigned pack4(float a, float b, float c, float d) {
  unsigned b0 = (unsigned)(a * 255.f + 0.5f);
  unsigned b1 = (unsigned)(b * 255.f + 0.5f);
  unsigned b2 = (unsigned)(c * 255.f + 0.5f);
  unsigned b3 = (unsigned)(d * 255.f + 0.5f);
  return b0 | (b1 << 8) | (b2 << 16) | (b3 << 24);
}
__device__ __forceinline__ void dotu8(float& sd, unsigned w, float4 p) {
  sd += (float)(w & 255u) * p.x + (float)((w >> 8) & 255u) * p.y +
        (float)((w >> 16) & 255u) * p.z + (float)(w >> 24) * p.w;
}

// ==== k_init: blocks 0..1023 mem0 copy + u->bf16 + sbias/unorm2; 1024..1087 A=Wk^T@Wq ==
__global__ __launch_bounds__(256) void k_init(
    const float* __restrict__ u, const float* __restrict__ sf,
    const float* __restrict__ mem0,
    const float* __restrict__ Wq, const float* __restrict__ Wk,
    const float* __restrict__ w1, const float* __restrict__ b1,
    const float* __restrict__ w2, const float* __restrict__ b2,
    float* __restrict__ wsf, u16* __restrict__ ubf, int use_ubf) {
  const int tid = threadIdx.x;
  if (blockIdx.x >= 1024) {
    // A[j,i] = sum_a Wk[a,j] * Wq[a,i];  block handles 8 j rows
    __shared__ float wkj[32][8];
    int j0 = (blockIdx.x - 1024) * 8;
    float acc[8][2] = {};
    for (int a0 = 0; a0 < cDA; a0 += 32) {
      wkj[tid >> 3][tid & 7] = Wk[(size_t)(a0 + (tid >> 3)) * cDU + j0 + (tid & 7)];
      __syncthreads();
#pragma unroll 8
      for (int aa = 0; aa < 32; ++aa) {
        float wq0 = Wq[(size_t)(a0 + aa) * cDM + tid * 2];
        float wq1 = Wq[(size_t)(a0 + aa) * cDM + tid * 2 + 1];
#pragma unroll
        for (int r = 0; r < 8; ++r) {
          acc[r][0] += wkj[aa][r] * wq0;
          acc[r][1] += wkj[aa][r] * wq1;
        }
      }
      __syncthreads();
    }
#pragma unroll
    for (int r = 0; r < 8; ++r) {
      wsf[F_A + (size_t)(j0 + r) * cDU + tid * 2] = acc[r][0];
      wsf[F_A + (size_t)(j0 + r) * cDU + tid * 2 + 1] = acc[r][1];
    }
    return;
  }
  const int gt = blockIdx.x * 256 + tid;
  const int nt = 1024 * 256;
  const int wv = tid >> 6, lane = tid & 63;
  const int gw = blockIdx.x * 4 + wv;
  const int nw = 1024 * 4;

  for (int i = gt; i < cB * cDM; i += nt) wsf[F_M0 + i] = mem0[i];

  if (use_ubf) {
    const int NU8 = cB * cT * cDU / 8;
    const float4* src = (const float4*)u;
    for (int c = gt; c < NU8; c += nt) {
      float4 f0 = src[(size_t)c * 2], f1 = src[(size_t)c * 2 + 1];
      u16x8 o;
      o[0] = f2bf(f0.x); o[1] = f2bf(f0.y); o[2] = f2bf(f0.z); o[3] = f2bf(f0.w);
      o[4] = f2bf(f1.x); o[5] = f2bf(f1.y); o[6] = f2bf(f1.z); o[7] = f2bf(f1.w);
      *(u16x8*)(ubf + (size_t)c * 8) = o;
    }
  }
  for (int row = gw; row < cB * cT; row += nw) {
    float d0 = sf[(size_t)row * cDF + 8];
    float d1 = sf[(size_t)row * cDF + 9];
    float d2 = sf[(size_t)row * cDF + 10];
    float acc = 0.f;
#pragma unroll
    for (int i = 0; i < 4; ++i) {
      int a = lane * 4 + i;
      float h = d0 * w1[a * 3 + 0] + d1 * w1[a * 3 + 1] + d2 * w1[a * 3 + 2] + b1[a];
      float g = 0.5f * h * (1.0f + erff(h * 0.70710678118654752f));
      acc += g * w2[a];
    }
    float un = 0.f;
    const float4* ur = (const float4*)(u + (size_t)row * cDU);
#pragma unroll
    for (int m = 0; m < 2; ++m) { float4 x = ur[lane + m * 64]; un += dot4(x, x); }
    acc = wave_sum(acc);
    un = wave_sum(un);
    if (lane == 0) { wsf[F_SB + row] = acc + b2[0]; wsf[F_UN + row] = un; }
  }
}

// =============== k_qk: qk[b,:] = A @ mem[b,:]; zero c_raw.  b = blockIdx&7 (XCD affin.)
__global__ __launch_bounds__(256) void k_qk(const float* __restrict__ A,
                                            const float* __restrict__ mem,
                                            float* __restrict__ qk,
                                            float* __restrict__ c_raw) {
  int wv = threadIdx.x >> 6, lane = threadIdx.x & 63;
  int b = blockIdx.x & 7;
  int j = (blockIdx.x >> 3) * 4 + wv;        // 0..511
  const float4* ar = (const float4*)(A + (size_t)j * cDM);
  const float4* mr = (const float4*)(mem + (size_t)b * cDM);
  float acc = dot4(ar[lane * 2], mr[lane * 2]) + dot4(ar[lane * 2 + 1], mr[lane * 2 + 1]);
  acc = wave_sum(acc);
  if (lane == 0) qk[b * cDU + j] = acc;
  int gt = blockIdx.x * 256 + threadIdx.x;
  if (gt < cB * cDU) c_raw[gt] = 0.f;
}

// =============== k_scores: logits = (u.qk/SCALE + sbias - g*sim@prev)/temp =============
// grid 1024; b = blockIdx&7 (XCD affinity). Each wave handles 4 rows with qk and
// prev held in registers (amortizes the 8 KB prev + 2 KB qk loads 4x, gives 4
// independent sim-row dots of ILP per wave).
__global__ __launch_bounds__(256) void k_scores(
    const u16* __restrict__ ubf, const float* __restrict__ uf,
    const float* __restrict__ qk, const float* __restrict__ sbias,
    const u8* __restrict__ sim8, const float* __restrict__ simf,
    const float* __restrict__ prev, const float* __restrict__ log_temp,
    float gamma, int use_ubf, int use_s8, float* __restrict__ logits) {
  int wv = threadIdx.x >> 6;
  int lane = threadIdx.x & 63;
  int b = blockIdx.x & 7;
  int t0 = ((blockIdx.x >> 3) * 4 + wv) * 4;   // 4 rows per wave
  const float4* qk4 = (const float4*)(qk + (size_t)b * cDU);
  float4 q0 = qk4[lane * 2], q1 = qk4[lane * 2 + 1];
  float4 pv[8];
  const bool haveP = (gamma != 0.0f) && use_s8;
  if (haveP) {
    const float4* pr4 = (const float4*)(prev + (size_t)b * cT);
#pragma unroll
    for (int m = 0; m < 2; ++m)
#pragma unroll
      for (int k = 0; k < 4; ++k) pv[m * 4 + k] = pr4[m * 256 + lane * 4 + k];
  }
  float temp = fminf(fmaxf(expf(log_temp[0]), 0.1f), 10.0f);
#pragma unroll
  for (int i = 0; i < 4; ++i) {
    int grow = b * cT + t0 + i;
    float acc;
    if (use_ubf) {
      u16x8 s = *(const u16x8*)(ubf + (size_t)grow * cDU + lane * 8);
      acc = bf2f(s[0]) * q0.x + bf2f(s[1]) * q0.y + bf2f(s[2]) * q0.z + bf2f(s[3]) * q0.w +
            bf2f(s[4]) * q1.x + bf2f(s[5]) * q1.y + bf2f(s[6]) * q1.z + bf2f(s[7]) * q1.w;
    } else {
      const float4* ur = (const float4*)(uf + (size_t)grow * cDU);
      acc = dot4(ur[lane * 2], q0) + dot4(ur[lane * 2 + 1], q1);
    }
    acc *= (1.0f / cSCALE);
    if (gamma != 0.0f) {
      float sd = 0.f;
      if (use_s8) {
        const u8* sr = sim8 + (size_t)grow * cT;
        uint4 sq0 = *(const uint4*)(sr + lane * 16);
        uint4 sq1 = *(const uint4*)(sr + 1024 + lane * 16);
        dotu8(sd, sq0.x, pv[0]); dotu8(sd, sq0.y, pv[1]);
        dotu8(sd, sq0.z, pv[2]); dotu8(sd, sq0.w, pv[3]);
        dotu8(sd, sq1.x, pv[4]); dotu8(sd, sq1.y, pv[5]);
        dotu8(sd, sq1.z, pv[6]); dotu8(sd, sq1.w, pv[7]);
        sd *= (1.0f / 255.0f);
      } else {
        const float4* sr = (const float4*)(simf + (size_t)grow * cT);
        const float4* pr4 = (const float4*)(prev + (size_t)b * cT);
#pragma unroll
        for (int m = 0; m < 8; ++m) sd += dot4(sr[lane + m * 64], pr4[lane + m * 64]);
      }
      acc -= gamma * sd;
    }
    acc = wave_sum(acc);
    if (lane == 0) logits[grow] = (acc + sbias[grow]) / temp;
  }
}

// =============== k_overlap: softmax(logits) once per 16 rows + overlap = sim @ y1 =====
// grid 1024, block 256; b = blockIdx&7, ch = blockIdx>>3 (0..127); 16 rows per block.
__global__ __launch_bounds__(256) void k_overlap(
    const u8* __restrict__ sim8c, u8* __restrict__ sim8w,
    const float* __restrict__ simf,
    const float* __restrict__ logits, int use_s8, int convert,
    float* __restrict__ overlap) {
  __shared__ float ylds[2176];   // padded: a = s + (s>>4)
  __shared__ float red[256];
  const int tid = threadIdx.x;
  const int wv = tid >> 6, lane = tid & 63;
  const int b = blockIdx.x & 7;
  const int ch = blockIdx.x >> 3;              // 0..127
  float l[8];
  float mx = -INFINITY;
#pragma unroll
  for (int e = 0; e < 8; ++e) { l[e] = logits[b * cT + e * 256 + tid]; mx = fmaxf(mx, l[e]); }
  red[tid] = mx; __syncthreads();
  for (int s2 = 128; s2; s2 >>= 1) { if (tid < s2) red[tid] = fmaxf(red[tid], red[tid + s2]); __syncthreads(); }
  mx = red[0]; __syncthreads();
  float sum = 0.f;
#pragma unroll
  for (int e = 0; e < 8; ++e) {
    float ev = expf(l[e] - mx);
    sum += ev;
    int s = e * 256 + tid;
    ylds[s + (s >> 4)] = ev;
  }
  red[tid] = sum; __syncthreads();
  for (int s2 = 128; s2; s2 >>= 1) { if (tid < s2) red[tid] += red[tid + s2]; __syncthreads(); }
  float invS = 1.f / red[0];
  __syncthreads();
  for (int r = 0; r < 4; ++r) {
    int row = b * cT + ch * 16 + wv * 4 + r;
    float acc = 0.f;
    if (use_s8 && !convert) {
#pragma unroll
      for (int m = 0; m < 2; ++m) {
        uint4 sq = *(const uint4*)(sim8c + (size_t)row * cT + m * 1024 + lane * 16);
        int s0 = m * 1024 + lane * 16;
#pragma unroll
        for (int k = 0; k < 4; ++k) {
          unsigned w = (&sq.x)[k];
          int s = s0 + k * 4;
          acc += (float)(w & 255u)         * ylds[s + (s >> 4)] +
                 (float)((w >> 8) & 255u)  * ylds[(s + 1) + ((s + 1) >> 4)] +
                 (float)((w >> 16) & 255u) * ylds[(s + 2) + ((s + 2) >> 4)] +
                 (float)(w >> 24)          * ylds[(s + 3) + ((s + 3) >> 4)];
        }
      }
      acc *= (1.0f / 255.0f);
    } else {
#pragma unroll
      for (int m = 0; m < 2; ++m) {
        const float4* sr = (const float4*)(simf + (size_t)row * cT + m * 1024 + lane * 16);
        uint4 oq;
#pragma unroll
        for (int k = 0; k < 4; ++k) {
          float4 sv = sr[k];
          int s = m * 1024 + lane * 16 + k * 4;
          acc += sv.x * ylds[s + (s >> 4)] + sv.y * ylds[(s + 1) + ((s + 1) >> 4)] +
                 sv.z * ylds[(s + 2) + ((s + 2) >> 4)] + sv.w * ylds[(s + 3) + ((s + 3) >> 4)];
          (&oq.x)[k] = pack4(sv.x, sv.y, sv.z, sv.w);
        }
        if (convert)
          *(uint4*)(sim8w + (size_t)row * cT + m * 1024 + lane * 16) = oq;
      }
    }
    acc = wave_sum(acc);
    if (lane == 0) overlap[row] = acc * invS;
  }
}

// =============== k_statcen: penalty+resoftmax+stats + centroid chunk accum =============
// grid 512: b = blockIdx&7, ch = blockIdx>>3 (0..63); 32 rows per block (8 per wave).
__global__ __launch_bounds__(256) void k_statcen(
    const float* __restrict__ overlap, const float* __restrict__ logits,
    const float* __restrict__ unorm2,
    const u16* __restrict__ ubf, const float* __restrict__ uf, int use_ubf,
    float* __restrict__ y, float* __restrict__ prev,
    float* __restrict__ scal, float* __restrict__ c_raw, int first_stage) {
  __shared__ float ylds[2048];
  __shared__ float comb[2048];
  __shared__ float red[256];
  const int tid = threadIdx.x;
  const int wv = tid >> 6, lane = tid & 63;
  const int b = blockIdx.x & 7;
  const int ch = blockIdx.x >> 3;              // 0..63
  float o[8], l[8], yv[8];
  float mo = -INFINITY;
#pragma unroll
  for (int e = 0; e < 8; ++e) { o[e] = overlap[b * cT + e * 256 + tid]; mo = fmaxf(mo, o[e]); }
  red[tid] = mo; __syncthreads();
  for (int s2 = 128; s2; s2 >>= 1) { if (tid < s2) red[tid] = fmaxf(red[tid], red[tid + s2]); __syncthreads(); }
  mo = fmaxf(red[0], cEPS); __syncthreads();
  float ml = -INFINITY;
#pragma unroll
  for (int e = 0; e < 8; ++e) { l[e] = logits[b * cT + e * 256 + tid] - o[e] / mo; ml = fmaxf(ml, l[e]); }
  red[tid] = ml; __syncthreads();
  for (int s2 = 128; s2; s2 >>= 1) { if (tid < s2) red[tid] = fmaxf(red[tid], red[tid + s2]); __syncthreads(); }
  ml = red[0]; __syncthreads();
  float sum = 0.f;
#pragma unroll
  for (int e = 0; e < 8; ++e) { l[e] = expf(l[e] - ml); sum += l[e]; }
  red[tid] = sum; __syncthreads();
  for (int s2 = 128; s2; s2 >>= 1) { if (tid < s2) red[tid] += red[tid + s2]; __syncthreads(); }
  float inv = 1.f / red[0]; __syncthreads();
  float ysr_p = 0.f, wsq_p = 0.f;
#pragma unroll
  for (int e = 0; e < 8; ++e) {
    yv[e] = l[e] * inv;
    ylds[e * 256 + tid] = yv[e];
    ysr_p += yv[e];
    wsq_p += yv[e] * unorm2[b * cT + e * 256 + tid];
  }
  red[tid] = ysr_p; __syncthreads();
  for (int s2 = 128; s2; s2 >>= 1) { if (tid < s2) red[tid] += red[tid + s2]; __syncthreads(); }
  float ysr = red[0]; __syncthreads();
  float ysc = fmaxf(ysr, cEPS);
  red[tid] = wsq_p; __syncthreads();
  for (int s2 = 128; s2; s2 >>= 1) { if (tid < s2) red[tid] += red[tid + s2]; __syncthreads(); }
  float wsq = red[0]; __syncthreads();
  float ent_p = 0.f;
#pragma unroll
  for (int e = 0; e < 8; ++e) {
    float yn = yv[e] / ysc;
    ent_p -= yn * logf(fmaxf(yn, cEPS));
  }
  red[tid] = ent_p; __syncthreads();
  for (int s2 = 128; s2; s2 >>= 1) { if (tid < s2) red[tid] += red[tid + s2]; __syncthreads(); }
  float ent = red[0]; __syncthreads();
  if (ch == 0) {
#pragma unroll
    for (int e = 0; e < 8; ++e) {
      int idx = b * cT + e * 256 + tid;
      y[idx] = yv[e];
      if (first_stage) prev[idx] = yv[e]; else prev[idx] += yv[e];
    }
    if (tid == 0) {
      scal[b * 8 + 0] = ysc;
      scal[b * 8 + 1] = ysr / (float)cT;
      scal[b * 8 + 2] = ent;
      scal[b * 8 + 3] = wsq;
    }
  }
  float acc[8] = {};
  for (int i = 0; i < 8; ++i) {
    int r = ch * 32 + wv * 8 + i;
    float yvv = ylds[r];
    int row = b * cT + r;
    if (use_ubf) {
      u16x8 s8 = *(const u16x8*)(ubf + (size_t)row * cDU + lane * 8);
#pragma unroll
      for (int e = 0; e < 8; ++e) acc[e] += yvv * bf2f(s8[e]);
    } else {
      const float4* ur = (const float4*)(uf + (size_t)row * cDU);
      float4 a0 = ur[lane * 2], a1 = ur[lane * 2 + 1];
      acc[0] += yvv * a0.x; acc[1] += yvv * a0.y; acc[2] += yvv * a0.z; acc[3] += yvv * a0.w;
      acc[4] += yvv * a1.x; acc[5] += yvv * a1.y; acc[6] += yvv * a1.z; acc[7] += yvv * a1.w;
    }
  }
  __syncthreads();
#pragma unroll
  for (int e = 0; e < 8; ++e) comb[wv * 512 + lane * 8 + e] = acc[e];
  __syncthreads();
  float s0 = comb[tid] + comb[512 + tid] + comb[1024 + tid] + comb[1536 + tid];
  float s1 = comb[tid + 256] + comb[512 + tid + 256] + comb[1024 + tid + 256] + comb[1536 + tid + 256];
  atomicAdd(&c_raw[b * cDU + tid], s0);
  atomicAdd(&c_raw[b * cDU + tid + 256], s1);
}

// =============== k_zyd: blocks 0..1023 -> z = c_raw@Wv^T ; 1024..2047 -> spread ======
// z-part: b = blk&7, j = (blk>>3)*4+wv.  spread: unit = blk-1024, b = unit&7,
// tc = unit>>3 (0..127); 16 rows per block, 4 per wave (short serial chains).
__global__ __launch_bounds__(256) void k_zyd(
    const float* __restrict__ c_raw, const float* __restrict__ Wv,
    const u16* __restrict__ ubf, const float* __restrict__ uf, int use_ubf,
    const float* __restrict__ unorm2, const float* __restrict__ y,
    float* __restrict__ z, float* __restrict__ scal, float* __restrict__ sprp) {
  __shared__ float s4[4];
  int wv = threadIdx.x >> 6, lane = threadIdx.x & 63;
  if (blockIdx.x < 1024) {
    int b = blockIdx.x & 7;
    int j = (blockIdx.x >> 3) * 4 + wv;      // 0..511
    const float4* c4 = (const float4*)(c_raw + (size_t)b * cDU);
    const float4* w4 = (const float4*)(Wv + (size_t)j * cDU);
    float acc = dot4(c4[lane * 2], w4[lane * 2]) + dot4(c4[lane * 2 + 1], w4[lane * 2 + 1]);
    acc = wave_sum(acc);
    if (lane == 0) z[b * cDU + j] = acc;
    return;
  }
  int unit = blockIdx.x - 1024;   // 0..1023
  int b = unit & 7, tc = unit >> 3;          // tc 0..127
  float ysc = scal[b * 8 + 0];
  float inv = 1.f / ysc;
  const float4* c4 = (const float4*)(c_raw + (size_t)b * cDU);
  float4 cr0 = c4[lane * 2], cr1 = c4[lane * 2 + 1];
  float4 cx0, cx1;
  cx0.x = cr0.x * inv; cx0.y = cr0.y * inv; cx0.z = cr0.z * inv; cx0.w = cr0.w * inv;
  cx1.x = cr1.x * inv; cx1.y = cr1.y * inv; cx1.z = cr1.z * inv; cx1.w = cr1.w * inv;
  float cen2 = wave_sum(dot4(cx0, cx0) + dot4(cx1, cx1));     // lane0-valid
  if (tc == 0 && wv == 0) {
    float csq = wave_sum(dot4(cr0, cr0) + dot4(cr1, cr1));
    if (lane == 0) scal[b * 8 + 6] = csq;
  }
  float part = 0.f;
  for (int i = 0; i < 4; ++i) {
    int row = b * cT + tc * 16 + wv * 4 + i;
    float dot;
    if (use_ubf) {
      u16x8 s = *(const u16x8*)(ubf + (size_t)row * cDU + lane * 8);
      dot = bf2f(s[0]) * cx0.x + bf2f(s[1]) * cx0.y + bf2f(s[2]) * cx0.z + bf2f(s[3]) * cx0.w +
            bf2f(s[4]) * cx1.x + bf2f(s[5]) * cx1.y + bf2f(s[6]) * cx1.z + bf2f(s[7]) * cx1.w;
    } else {
      const float4* ur = (const float4*)(uf + (size_t)row * cDU);
      dot = dot4(ur[lane * 2], cx0) + dot4(ur[lane * 2 + 1], cx1);
    }
    dot = wave_sum(dot);
    if (lane == 0) {
      float d2 = unorm2[row] - 2.f * dot + cen2;
      part += y[row] * sqrtf(fmaxf(d2, 0.f));
    }
  }
  if (lane == 0) s4[wv] = part;
  __syncthreads();
  if (threadIdx.x == 0) sprp[b * 128 + tc] = s4[0] + s4[1] + s4[2] + s4[3];
}

// =============== k_gru: gates + memory update + output (wave per (b,i)) ==============
__global__ __launch_bounds__(256) void k_gru(const float* __restrict__ z,
                                             const float* __restrict__ scal,
                                             const float* __restrict__ sprp,
                                             const float* __restrict__ memin,
                                             float* __restrict__ memout,
                                             const float* __restrict__ W_ih,
                                             const float* __restrict__ b_ih,
                                             const float* __restrict__ W_hh,
                                             const float* __restrict__ b_hh,
                                             float* __restrict__ out, int stage) {
  int wid = blockIdx.x * 4 + (threadIdx.x >> 6);
  int lane = threadIdx.x & 63;
  int b = wid >> 9, i = wid & 511;
  const float4* xz = (const float4*)(z + (size_t)b * cDU);
  const float4* xm = (const float4*)(memin + (size_t)b * cDM);
  float4 z0 = xz[lane * 2], z1 = xz[lane * 2 + 1];
  float4 m0 = xm[lane * 2], m1 = xm[lane * 2 + 1];
  float ysc = scal[b * 8 + 0];
  float sv = sprp[b * 128 + lane] + sprp[b * 128 + 64 + lane];
  float spr_raw = wave_sum(sv);
  float aI[3], aH[3];
#pragma unroll
  for (int g = 0; g < 3; ++g) {
    size_t row = (size_t)(g * 512 + i);
    const float4* wI = (const float4*)(W_ih + row * 516);
    float a = dot4(z0, wI[lane * 2]) + dot4(z1, wI[lane * 2 + 1]);
    if (lane == 0) {
      float4 wt = wI[128];
      float cov = scal[b * 8 + 1], ent = scal[b * 8 + 2];
      float spr = spr_raw / ysc;
      float cmp = 2.f * (ysc * scal[b * 8 + 3] - scal[b * 8 + 6]) / fmaxf(ysc * ysc, cEPS);
      a += cov * wt.x + ent * wt.y + spr * wt.z + cmp * wt.w;
    }
    aI[g] = wave_sum(a);
    const float4* wH = (const float4*)(W_hh + row * cDM);
    float h = dot4(m0, wH[lane * 2]) + dot4(m1, wH[lane * 2 + 1]);
    aH[g] = wave_sum(h);
  }
  if (lane == 0) {
    float gir = aI[0] + b_ih[i],        ghr = aH[0] + b_hh[i];
    float giz = aI[1] + b_ih[512 + i],  ghz = aH[1] + b_hh[512 + i];
    float gin = aI[2] + b_ih[1024 + i], ghn = aH[2] + b_hh[1024 + i];
    float rg = 1.f / (1.f + expf(-(gir + ghr)));
    float zg = 1.f / (1.f + expf(-(giz + ghz)));
    float ng = tanhf(gin + rg * ghn);
    float mold = memin[b * cDM + i];
    memout[b * cDM + i] = (1.f - zg) * ng + zg * mold;
    out[(size_t)(b * cL + stage) * cDU + i] = z[b * cDU + i];
  }
}

extern "C" void kernel_launch(void* const* d_in, const int* in_sizes, int n_in,
                              void* d_out, int out_size, void* d_ws, size_t ws_size,
                              hipStream_t stream) {
  const float* u    = (const float*)d_in[0];
  const float* sf   = (const float*)d_in[1];
  const float* sim  = (const float*)d_in[2];
  const float* mem0 = (const float*)d_in[3];
  const float* Wq   = (const float*)d_in[4];
  const float* Wk   = (const float*)d_in[5];
  const float* Wv   = (const float*)d_in[6];
  const float* sbw1 = (const float*)d_in[7];
  const float* sbb1 = (const float*)d_in[8];
  const float* sbw2 = (const float*)d_in[9];
  const float* sbb2 = (const float*)d_in[10];
  const float* logt = (const float*)d_in[11];
  const float* W_ih = (const float*)d_in[12];
  const float* b_ih = (const float*)d_in[13];
  const float* W_hh = (const float*)d_in[14];
  const float* b_hh = (const float*)d_in[15];
  float* out = (float*)d_out;
  float* ws  = (float*)d_ws;
  u16* ubf  = (u16*)((char*)d_ws + U_OFFB);
  u8* sim8  = (u8*)((char*)d_ws + S8_OFFB);

  const int use_ubf = (ws_size >= WS_NEED_U) ? 1 : 0;
  const int use_s8  = (ws_size >= WS_NEED_ALL) ? 1 : 0;

  k_init<<<1088, 256, 0, stream>>>(u, sf, mem0, Wq, Wk, sbw1, sbb1, sbw2, sbb2,
                                   ws, ubf, use_ubf);

  for (int stage = 0; stage < cL; ++stage) {
    float* mcur = ws + ((stage & 1) ? F_M1 : F_M0);
    float* mnxt = ws + ((stage & 1) ? F_M0 : F_M1);
    k_qk<<<1024, 256, 0, stream>>>(ws + F_A, mcur, ws + F_QK, ws + F_C);
    k_scores<<<1024, 256, 0, stream>>>(ubf, u, ws + F_QK, ws + F_SB, sim8, sim,
                                       ws + F_PR, logt, stage == 0 ? 0.0f : cGAMMA,
                                       use_ubf, use_s8, ws + F_LG);
    k_overlap<<<1024, 256, 0, stream>>>(sim8, sim8, sim, ws + F_LG, use_s8,
                                        (stage == 0 && use_s8) ? 1 : 0, ws + F_OV);
    k_statcen<<<512, 256, 0, stream>>>(ws + F_OV, ws + F_LG, ws + F_UN,
                                       ubf, u, use_ubf,
                                       ws + F_Y, ws + F_PR, ws + F_SC, ws + F_C,
                                       stage == 0 ? 1 : 0);
    k_zyd<<<2048, 256, 0, stream>>>(ws + F_C, Wv, ubf, u, use_ubf,
                                    ws + F_UN, ws + F_Y, ws + F_Z, ws + F_SC, ws + F_SP);
    k_gru<<<1024, 256, 0, stream>>>(ws + F_Z, ws + F_SC, ws + F_SP, mcur, mnxt,
                                    W_ih, b_ih, W_hh, b_hh, out, stage);
  }
}

// Round 6
// 460.969 us; speedup vs baseline: 4.0042x; 1.0066x over previous
//
#include <hip/hip_runtime.h>
#include <math.h>

constexpr int cB = 8, cT = 2048, cDU = 512, cDM = 512, cDA = 256, cDF = 12, cL = 4;
constexpr float cEPS = 1e-6f;
constexpr float cSCALE = 16.0f;   // sqrt(DA)
constexpr float cGAMMA = 1.0f;

typedef unsigned short u16;
typedef unsigned char u8;
typedef u16 u16x8 __attribute__((ext_vector_type(8)));

// ---------------- workspace layout (float offsets) ----------------
constexpr size_t F_SB = 0;                 // sbias  B*T
constexpr size_t F_UN = F_SB + 16384;      // unorm2 B*T
constexpr size_t F_LG = F_UN + 16384;      // logits B*T
constexpr size_t F_Y  = F_LG + 16384;      // y (final, per stage) B*T
constexpr size_t F_PR = F_Y  + 16384;      // prev   B*T
constexpr size_t F_OV = F_PR + 16384;      // overlap B*T
constexpr size_t F_SP = F_OV + 16384;      // spread partials B*128
constexpr size_t F_QK = F_SP + 1024;       // qk  B*DU
constexpr size_t F_M0 = F_QK + 4096;       // memory buf 0
constexpr size_t F_M1 = F_M0 + 4096;       // memory buf 1
constexpr size_t F_C  = F_M1 + 4096;       // c_raw B*DU
constexpr size_t F_Z  = F_C  + 4096;       // z B*DU
constexpr size_t F_SC = F_Z  + 4096;       // scalars B*8
constexpr size_t F_A  = F_SC + 64;         // A = Wk^T @ Wq, 512x512
constexpr size_t F_END = F_A + 262144;
constexpr size_t U_OFFB   = F_END * 4;                       // bf16 u
constexpr size_t U_BYTES  = (size_t)cB * cT * cDU * 2;
constexpr size_t S8_OFFB  = U_OFFB + U_BYTES;                // u8 sim
constexpr size_t S8_BYTES = (size_t)cB * cT * cT;
constexpr size_t WS_NEED_U   = S8_OFFB;
constexpr size_t WS_NEED_ALL = S8_OFFB + S8_BYTES;
// scal: 0 ysum_clamped, 1 coverage, 2 entropy, 3 wsq, 6 csq

__device__ __forceinline__ float wave_sum(float v) {
#pragma unroll
  for (int o = 32; o; o >>= 1) v += __shfl_down(v, o);
  return v;   // valid on lane 0
}
__device__ __forceinline__ float wave_max(float v) {
#pragma unroll
  for (int o = 32; o; o >>= 1) v = fmaxf(v, __shfl_down(v, o));
  return v;   // valid on lane 0
}
// Block reductions via wave shuffle + 4-slot combine. Each call uses its OWN slot
// (4 floats) so there is no reuse hazard; exactly 1 barrier per reduction.
__device__ __forceinline__ float blk_sum4(float v, float* slot, int wv, int lane) {
  v = wave_sum(v);
  if (lane == 0) slot[wv] = v;
  __syncthreads();
  return slot[0] + slot[1] + slot[2] + slot[3];
}
__device__ __forceinline__ float blk_max4(float v, float* slot, int wv, int lane) {
  v = wave_max(v);
  if (lane == 0) slot[wv] = v;
  __syncthreads();
  return fmaxf(fmaxf(slot[0], slot[1]), fmaxf(slot[2], slot[3]));
}
__device__ __forceinline__ u16 f2bf(float f) {
  unsigned u = __float_as_uint(f);
  return (u16)((u + 0x7fffu + ((u >> 16) & 1u)) >> 16);
}
__device__ __forceinline__ float bf2f(u16 h) { return __uint_as_float(((unsigned)h) << 16); }
__device__ __forceinline__ float dot4(float4 a, float4 b) {
  return a.x * b.x + a.y * b.y + a.z * b.z + a.w * b.w;
}
__device__ __forceinline__ unsigned pack4(float a, float b, float c, float d) {
  unsigned b0 = (unsigned)(a * 255.f + 0.5f);
  unsigned b1 = (unsigned)(b * 255.f + 0.5f);
  unsigned b2 = (unsigned)(c * 255.f + 0.5f);
  unsigned b3 = (unsigned)(d * 255.f + 0.5f);
  return b0 | (b1 << 8) | (b2 << 16) | (b3 << 24);
}
__device__ __forceinline__ void dotu8(float& sd, unsigned w, float4 p) {
  sd += (float)(w & 255u) * p.x + (float)((w >> 8) & 255u) * p.y +
        (float)((w >> 16) & 255u) * p.z + (float)(w >> 24) * p.w;
}

// ==== k_init: blocks 0..1023 mem0 copy + u->bf16 + sbias/unorm2; 1024..1087 A=Wk^T@Wq ==
__global__ __launch_bounds__(256) void k_init(
    const float* __restrict__ u, const float* __restrict__ sf,
    const float* __restrict__ mem0,
    const float* __restrict__ Wq, const float* __restrict__ Wk,
    const float* __restrict__ w1, const float* __restrict__ b1,
    const float* __restrict__ w2, const float* __restrict__ b2,
    float* __restrict__ wsf, u16* __restrict__ ubf, int use_ubf) {
  const int tid = threadIdx.x;
  if (blockIdx.x >= 1024) {
    // A[j,i] = sum_a Wk[a,j] * Wq[a,i];  block handles 8 j rows
    __shared__ float wkj[32][8];
    int j0 = (blockIdx.x - 1024) * 8;
    float acc[8][2] = {};
    for (int a0 = 0; a0 < cDA; a0 += 32) {
      wkj[tid >> 3][tid & 7] = Wk[(size_t)(a0 + (tid >> 3)) * cDU + j0 + (tid & 7)];
      __syncthreads();
#pragma unroll 8
      for (int aa = 0; aa < 32; ++aa) {
        float wq0 = Wq[(size_t)(a0 + aa) * cDM + tid * 2];
        float wq1 = Wq[(size_t)(a0 + aa) * cDM + tid * 2 + 1];
#pragma unroll
        for (int r = 0; r < 8; ++r) {
          acc[r][0] += wkj[aa][r] * wq0;
          acc[r][1] += wkj[aa][r] * wq1;
        }
      }
      __syncthreads();
    }
#pragma unroll
    for (int r = 0; r < 8; ++r) {
      wsf[F_A + (size_t)(j0 + r) * cDU + tid * 2] = acc[r][0];
      wsf[F_A + (size_t)(j0 + r) * cDU + tid * 2 + 1] = acc[r][1];
    }
    return;
  }
  const int gt = blockIdx.x * 256 + tid;
  const int nt = 1024 * 256;
  const int wv = tid >> 6, lane = tid & 63;
  const int gw = blockIdx.x * 4 + wv;
  const int nw = 1024 * 4;

  for (int i = gt; i < cB * cDM; i += nt) wsf[F_M0 + i] = mem0[i];

  if (use_ubf) {
    const int NU8 = cB * cT * cDU / 8;
    const float4* src = (const float4*)u;
    for (int c = gt; c < NU8; c += nt) {
      float4 f0 = src[(size_t)c * 2], f1 = src[(size_t)c * 2 + 1];
      u16x8 o;
      o[0] = f2bf(f0.x); o[1] = f2bf(f0.y); o[2] = f2bf(f0.z); o[3] = f2bf(f0.w);
      o[4] = f2bf(f1.x); o[5] = f2bf(f1.y); o[6] = f2bf(f1.z); o[7] = f2bf(f1.w);
      *(u16x8*)(ubf + (size_t)c * 8) = o;
    }
  }
  for (int row = gw; row < cB * cT; row += nw) {
    float d0 = sf[(size_t)row * cDF + 8];
    float d1 = sf[(size_t)row * cDF + 9];
    float d2 = sf[(size_t)row * cDF + 10];
    float acc = 0.f;
#pragma unroll
    for (int i = 0; i < 4; ++i) {
      int a = lane * 4 + i;
      float h = d0 * w1[a * 3 + 0] + d1 * w1[a * 3 + 1] + d2 * w1[a * 3 + 2] + b1[a];
      float g = 0.5f * h * (1.0f + erff(h * 0.70710678118654752f));
      acc += g * w2[a];
    }
    float un = 0.f;
    const float4* ur = (const float4*)(u + (size_t)row * cDU);
#pragma unroll
    for (int m = 0; m < 2; ++m) { float4 x = ur[lane + m * 64]; un += dot4(x, x); }
    acc = wave_sum(acc);
    un = wave_sum(un);
    if (lane == 0) { wsf[F_SB + row] = acc + b2[0]; wsf[F_UN + row] = un; }
  }
}

// =============== k_qk: qk[b,:] = A @ mem[b,:]; zero c_raw.  b = blockIdx&7 (XCD affin.)
__global__ __launch_bounds__(256) void k_qk(const float* __restrict__ A,
                                            const float* __restrict__ mem,
                                            float* __restrict__ qk,
                                            float* __restrict__ c_raw) {
  int wv = threadIdx.x >> 6, lane = threadIdx.x & 63;
  int b = blockIdx.x & 7;
  int j = (blockIdx.x >> 3) * 4 + wv;        // 0..511
  const float4* ar = (const float4*)(A + (size_t)j * cDM);
  const float4* mr = (const float4*)(mem + (size_t)b * cDM);
  float acc = dot4(ar[lane * 2], mr[lane * 2]) + dot4(ar[lane * 2 + 1], mr[lane * 2 + 1]);
  acc = wave_sum(acc);
  if (lane == 0) qk[b * cDU + j] = acc;
  int gt = blockIdx.x * 256 + threadIdx.x;
  if (gt < cB * cDU) c_raw[gt] = 0.f;
}

// =============== k_scores: logits = (u.qk/SCALE + sbias - g*sim@prev)/temp =============
// grid 512; b = blockIdx&7 (XCD affinity). Each wave handles 8 rows with qk and
// prev held in registers (amortizes the 8 KB prev + 2 KB qk loads 8x; 8
// independent sim-row streams of ILP per wave against L3 latency).
__global__ __launch_bounds__(256) void k_scores(
    const u16* __restrict__ ubf, const float* __restrict__ uf,
    const float* __restrict__ qk, const float* __restrict__ sbias,
    const u8* __restrict__ sim8, const float* __restrict__ simf,
    const float* __restrict__ prev, const float* __restrict__ log_temp,
    float gamma, int use_ubf, int use_s8, float* __restrict__ logits) {
  int wv = threadIdx.x >> 6;
  int lane = threadIdx.x & 63;
  int b = blockIdx.x & 7;
  int t0 = ((blockIdx.x >> 3) * 4 + wv) * 8;   // 8 rows per wave
  const float4* qk4 = (const float4*)(qk + (size_t)b * cDU);
  float4 q0 = qk4[lane * 2], q1 = qk4[lane * 2 + 1];
  float4 pv[8];
  const bool haveP = (gamma != 0.0f) && use_s8;
  if (haveP) {
    const float4* pr4 = (const float4*)(prev + (size_t)b * cT);
#pragma unroll
    for (int m = 0; m < 2; ++m)
#pragma unroll
      for (int k = 0; k < 4; ++k) pv[m * 4 + k] = pr4[m * 256 + lane * 4 + k];
  }
  float temp = fminf(fmaxf(expf(log_temp[0]), 0.1f), 10.0f);
#pragma unroll
  for (int i = 0; i < 8; ++i) {
    int grow = b * cT + t0 + i;
    float acc;
    if (use_ubf) {
      u16x8 s = *(const u16x8*)(ubf + (size_t)grow * cDU + lane * 8);
      acc = bf2f(s[0]) * q0.x + bf2f(s[1]) * q0.y + bf2f(s[2]) * q0.z + bf2f(s[3]) * q0.w +
            bf2f(s[4]) * q1.x + bf2f(s[5]) * q1.y + bf2f(s[6]) * q1.z + bf2f(s[7]) * q1.w;
    } else {
      const float4* ur = (const float4*)(uf + (size_t)grow * cDU);
      acc = dot4(ur[lane * 2], q0) + dot4(ur[lane * 2 + 1], q1);
    }
    acc *= (1.0f / cSCALE);
    if (gamma != 0.0f) {
      float sd = 0.f;
      if (use_s8) {
        const u8* sr = sim8 + (size_t)grow * cT;
        uint4 sq0 = *(const uint4*)(sr + lane * 16);
        uint4 sq1 = *(const uint4*)(sr + 1024 + lane * 16);
        dotu8(sd, sq0.x, pv[0]); dotu8(sd, sq0.y, pv[1]);
        dotu8(sd, sq0.z, pv[2]); dotu8(sd, sq0.w, pv[3]);
        dotu8(sd, sq1.x, pv[4]); dotu8(sd, sq1.y, pv[5]);
        dotu8(sd, sq1.z, pv[6]); dotu8(sd, sq1.w, pv[7]);
        sd *= (1.0f / 255.0f);
      } else {
        const float4* sr = (const float4*)(simf + (size_t)grow * cT);
        const float4* pr4 = (const float4*)(prev + (size_t)b * cT);
#pragma unroll
        for (int m = 0; m < 8; ++m) sd += dot4(sr[lane + m * 64], pr4[lane + m * 64]);
      }
      acc -= gamma * sd;
    }
    acc = wave_sum(acc);
    if (lane == 0) logits[grow] = (acc + sbias[grow]) / temp;
  }
}

// =============== k_overlap: softmax(logits) once per 16 rows + overlap = sim @ y1 =====
// grid 1024, block 256; b = blockIdx&7, ch = blockIdx>>3 (0..127); 16 rows per block.
__global__ __launch_bounds__(256) void k_overlap(
    const u8* __restrict__ sim8c, u8* __restrict__ sim8w,
    const float* __restrict__ simf,
    const float* __restrict__ logits, int use_s8, int convert,
    float* __restrict__ overlap) {
  __shared__ float ylds[2176];   // padded: a = s + (s>>4)
  __shared__ float slots[2][4];
  const int tid = threadIdx.x;
  const int wv = tid >> 6, lane = tid & 63;
  const int b = blockIdx.x & 7;
  const int ch = blockIdx.x >> 3;              // 0..127
  float l[8];
  float mx = -INFINITY;
#pragma unroll
  for (int e = 0; e < 8; ++e) { l[e] = logits[b * cT + e * 256 + tid]; mx = fmaxf(mx, l[e]); }
  mx = blk_max4(mx, slots[0], wv, lane);
  float sum = 0.f;
#pragma unroll
  for (int e = 0; e < 8; ++e) {
    float ev = __expf(l[e] - mx);
    sum += ev;
    int s = e * 256 + tid;
    ylds[s + (s >> 4)] = ev;
  }
  sum = blk_sum4(sum, slots[1], wv, lane);   // barrier also publishes ylds
  float invS = 1.f / sum;
  for (int r = 0; r < 4; ++r) {
    int row = b * cT + ch * 16 + wv * 4 + r;
    float acc = 0.f;
    if (use_s8 && !convert) {
#pragma unroll
      for (int m = 0; m < 2; ++m) {
        uint4 sq = *(const uint4*)(sim8c + (size_t)row * cT + m * 1024 + lane * 16);
        int s0 = m * 1024 + lane * 16;
#pragma unroll
        for (int k = 0; k < 4; ++k) {
          unsigned w = (&sq.x)[k];
          int s = s0 + k * 4;
          acc += (float)(w & 255u)         * ylds[s + (s >> 4)] +
                 (float)((w >> 8) & 255u)  * ylds[(s + 1) + ((s + 1) >> 4)] +
                 (float)((w >> 16) & 255u) * ylds[(s + 2) + ((s + 2) >> 4)] +
                 (float)(w >> 24)          * ylds[(s + 3) + ((s + 3) >> 4)];
        }
      }
      acc *= (1.0f / 255.0f);
    } else {
#pragma unroll
      for (int m = 0; m < 2; ++m) {
        const float4* sr = (const float4*)(simf + (size_t)row * cT + m * 1024 + lane * 16);
        uint4 oq;
#pragma unroll
        for (int k = 0; k < 4; ++k) {
          float4 sv = sr[k];
          int s = m * 1024 + lane * 16 + k * 4;
          acc += sv.x * ylds[s + (s >> 4)] + sv.y * ylds[(s + 1) + ((s + 1) >> 4)] +
                 sv.z * ylds[(s + 2) + ((s + 2) >> 4)] + sv.w * ylds[(s + 3) + ((s + 3) >> 4)];
          (&oq.x)[k] = pack4(sv.x, sv.y, sv.z, sv.w);
        }
        if (convert)
          *(uint4*)(sim8w + (size_t)row * cT + m * 1024 + lane * 16) = oq;
      }
    }
    acc = wave_sum(acc);
    if (lane == 0) overlap[row] = acc * invS;
  }
}

// =============== k_statcen: penalty+resoftmax+stats + centroid chunk accum =============
// grid 512: b = blockIdx&7, ch = blockIdx>>3 (0..63); 32 rows per block (8 per wave).
__global__ __launch_bounds__(256) void k_statcen(
    const float* __restrict__ overlap, const float* __restrict__ logits,
    const float* __restrict__ unorm2,
    const u16* __restrict__ ubf, const float* __restrict__ uf, int use_ubf,
    float* __restrict__ y, float* __restrict__ prev,
    float* __restrict__ scal, float* __restrict__ c_raw, int first_stage) {
  __shared__ float ylds[2048];
  __shared__ float comb[2048];
  __shared__ float slots[6][4];
  const int tid = threadIdx.x;
  const int wv = tid >> 6, lane = tid & 63;
  const int b = blockIdx.x & 7;
  const int ch = blockIdx.x >> 3;              // 0..63
  float o[8], l[8], yv[8];
  float mo = -INFINITY;
#pragma unroll
  for (int e = 0; e < 8; ++e) { o[e] = overlap[b * cT + e * 256 + tid]; mo = fmaxf(mo, o[e]); }
  mo = fmaxf(blk_max4(mo, slots[0], wv, lane), cEPS);
  float ml = -INFINITY;
#pragma unroll
  for (int e = 0; e < 8; ++e) { l[e] = logits[b * cT + e * 256 + tid] - o[e] / mo; ml = fmaxf(ml, l[e]); }
  ml = blk_max4(ml, slots[1], wv, lane);
  float sum = 0.f;
#pragma unroll
  for (int e = 0; e < 8; ++e) { l[e] = __expf(l[e] - ml); sum += l[e]; }
  sum = blk_sum4(sum, slots[2], wv, lane);
  float inv = 1.f / sum;
  float ysr_p = 0.f, wsq_p = 0.f;
#pragma unroll
  for (int e = 0; e < 8; ++e) {
    yv[e] = l[e] * inv;
    ylds[e * 256 + tid] = yv[e];
    ysr_p += yv[e];
    wsq_p += yv[e] * unorm2[b * cT + e * 256 + tid];
  }
  float ysr = blk_sum4(ysr_p, slots[3], wv, lane);   // barrier also publishes ylds
  float ysc = fmaxf(ysr, cEPS);
  float wsq = blk_sum4(wsq_p, slots[4], wv, lane);
  float ent_p = 0.f;
#pragma unroll
  for (int e = 0; e < 8; ++e) {
    float yn = yv[e] / ysc;
    ent_p -= yn * __logf(fmaxf(yn, cEPS));
  }
  float ent = blk_sum4(ent_p, slots[5], wv, lane);
  if (ch == 0) {
#pragma unroll
    for (int e = 0; e < 8; ++e) {
      int idx = b * cT + e * 256 + tid;
      y[idx] = yv[e];
      if (first_stage) prev[idx] = yv[e]; else prev[idx] += yv[e];
    }
    if (tid == 0) {
      scal[b * 8 + 0] = ysc;
      scal[b * 8 + 1] = ysr / (float)cT;
      scal[b * 8 + 2] = ent;
      scal[b * 8 + 3] = wsq;
    }
  }
  float acc[8] = {};
  for (int i = 0; i < 8; ++i) {
    int r = ch * 32 + wv * 8 + i;
    float yvv = ylds[r];
    int row = b * cT + r;
    if (use_ubf) {
      u16x8 s8 = *(const u16x8*)(ubf + (size_t)row * cDU + lane * 8);
#pragma unroll
      for (int e = 0; e < 8; ++e) acc[e] += yvv * bf2f(s8[e]);
    } else {
      const float4* ur = (const float4*)(uf + (size_t)row * cDU);
      float4 a0 = ur[lane * 2], a1 = ur[lane * 2 + 1];
      acc[0] += yvv * a0.x; acc[1] += yvv * a0.y; acc[2] += yvv * a0.z; acc[3] += yvv * a0.w;
      acc[4] += yvv * a1.x; acc[5] += yvv * a1.y; acc[6] += yvv * a1.z; acc[7] += yvv * a1.w;
    }
  }
  __syncthreads();
#pragma unroll
  for (int e = 0; e < 8; ++e) comb[wv * 512 + lane * 8 + e] = acc[e];
  __syncthreads();
  float s0 = comb[tid] + comb[512 + tid] + comb[1024 + tid] + comb[1536 + tid];
  float s1 = comb[tid + 256] + comb[512 + tid + 256] + comb[1024 + tid + 256] + comb[1536 + tid + 256];
  atomicAdd(&c_raw[b * cDU + tid], s0);
  atomicAdd(&c_raw[b * cDU + tid + 256], s1);
}

// =============== k_zyd: blocks 0..1023 -> z = c_raw@Wv^T ; 1024..2047 -> spread ======
// z-part: b = blk&7, j = (blk>>3)*4+wv.  spread: unit = blk-1024, b = unit&7,
// tc = unit>>3 (0..127); 16 rows per block, 4 per wave (short serial chains).
__global__ __launch_bounds__(256) void k_zyd(
    const float* __restrict__ c_raw, const float* __restrict__ Wv,
    const u16* __restrict__ ubf, const float* __restrict__ uf, int use_ubf,
    const float* __restrict__ unorm2, const float* __restrict__ y,
    float* __restrict__ z, float* __restrict__ scal, float* __restrict__ sprp) {
  __shared__ float s4[4];
  int wv = threadIdx.x >> 6, lane = threadIdx.x & 63;
  if (blockIdx.x < 1024) {
    int b = blockIdx.x & 7;
    int j = (blockIdx.x >> 3) * 4 + wv;      // 0..511
    const float4* c4 = (const float4*)(c_raw + (size_t)b * cDU);
    const float4* w4 = (const float4*)(Wv + (size_t)j * cDU);
    float acc = dot4(c4[lane * 2], w4[lane * 2]) + dot4(c4[lane * 2 + 1], w4[lane * 2 + 1]);
    acc = wave_sum(acc);
    if (lane == 0) z[b * cDU + j] = acc;
    return;
  }
  int unit = blockIdx.x - 1024;   // 0..1023
  int b = unit & 7, tc = unit >> 3;          // tc 0..127
  float ysc = scal[b * 8 + 0];
  float inv = 1.f / ysc;
  const float4* c4 = (const float4*)(c_raw + (size_t)b * cDU);
  float4 cr0 = c4[lane * 2], cr1 = c4[lane * 2 + 1];
  float4 cx0, cx1;
  cx0.x = cr0.x * inv; cx0.y = cr0.y * inv; cx0.z = cr0.z * inv; cx0.w = cr0.w * inv;
  cx1.x = cr1.x * inv; cx1.y = cr1.y * inv; cx1.z = cr1.z * inv; cx1.w = cr1.w * inv;
  float cen2 = wave_sum(dot4(cx0, cx0) + dot4(cx1, cx1));     // lane0-valid
  if (tc == 0 && wv == 0) {
    float csq = wave_sum(dot4(cr0, cr0) + dot4(cr1, cr1));
    if (lane == 0) scal[b * 8 + 6] = csq;
  }
  float part = 0.f;
  for (int i = 0; i < 4; ++i) {
    int row = b * cT + tc * 16 + wv * 4 + i;
    float dot;
    if (use_ubf) {
      u16x8 s = *(const u16x8*)(ubf + (size_t)row * cDU + lane * 8);
      dot = bf2f(s[0]) * cx0.x + bf2f(s[1]) * cx0.y + bf2f(s[2]) * cx0.z + bf2f(s[3]) * cx0.w +
            bf2f(s[4]) * cx1.x + bf2f(s[5]) * cx1.y + bf2f(s[6]) * cx1.z + bf2f(s[7]) * cx1.w;
    } else {
      const float4* ur = (const float4*)(uf + (size_t)row * cDU);
      dot = dot4(ur[lane * 2], cx0) + dot4(ur[lane * 2 + 1], cx1);
    }
    dot = wave_sum(dot);
    if (lane == 0) {
      float d2 = unorm2[row] - 2.f * dot + cen2;
      part += y[row] * sqrtf(fmaxf(d2, 0.f));
    }
  }
  if (lane == 0) s4[wv] = part;
  __syncthreads();
  if (threadIdx.x == 0) sprp[b * 128 + tc] = s4[0] + s4[1] + s4[2] + s4[3];
}

// =============== k_gru: gates + memory update + output (wave per (b,i)) ==============
__global__ __launch_bounds__(256) void k_gru(const float* __restrict__ z,
                                             const float* __restrict__ scal,
                                             const float* __restrict__ sprp,
                                             const float* __restrict__ memin,
                                             float* __restrict__ memout,
                                             const float* __restrict__ W_ih,
                                             const float* __restrict__ b_ih,
                                             const float* __restrict__ W_hh,
                                             const float* __restrict__ b_hh,
                                             float* __restrict__ out, int stage) {
  int wid = blockIdx.x * 4 + (threadIdx.x >> 6);
  int lane = threadIdx.x & 63;
  int b = wid >> 9, i = wid & 511;
  const float4* xz = (const float4*)(z + (size_t)b * cDU);
  const float4* xm = (const float4*)(memin + (size_t)b * cDM);
  float4 z0 = xz[lane * 2], z1 = xz[lane * 2 + 1];
  float4 m0 = xm[lane * 2], m1 = xm[lane * 2 + 1];
  float ysc = scal[b * 8 + 0];
  float sv = sprp[b * 128 + lane] + sprp[b * 128 + 64 + lane];
  float spr_raw = wave_sum(sv);
  float aI[3], aH[3];
#pragma unroll
  for (int g = 0; g < 3; ++g) {
    size_t row = (size_t)(g * 512 + i);
    const float4* wI = (const float4*)(W_ih + row * 516);
    float a = dot4(z0, wI[lane * 2]) + dot4(z1, wI[lane * 2 + 1]);
    if (lane == 0) {
      float4 wt = wI[128];
      float cov = scal[b * 8 + 1], ent = scal[b * 8 + 2];
      float spr = spr_raw / ysc;
      float cmp = 2.f * (ysc * scal[b * 8 + 3] - scal[b * 8 + 6]) / fmaxf(ysc * ysc, cEPS);
      a += cov * wt.x + ent * wt.y + spr * wt.z + cmp * wt.w;
    }
    aI[g] = wave_sum(a);
    const float4* wH = (const float4*)(W_hh + row * cDM);
    float h = dot4(m0, wH[lane * 2]) + dot4(m1, wH[lane * 2 + 1]);
    aH[g] = wave_sum(h);
  }
  if (lane == 0) {
    float gir = aI[0] + b_ih[i],        ghr = aH[0] + b_hh[i];
    float giz = aI[1] + b_ih[512 + i],  ghz = aH[1] + b_hh[512 + i];
    float gin = aI[2] + b_ih[1024 + i], ghn = aH[2] + b_hh[1024 + i];
    float rg = 1.f / (1.f + expf(-(gir + ghr)));
    float zg = 1.f / (1.f + expf(-(giz + ghz)));
    float ng = tanhf(gin + rg * ghn);
    float mold = memin[b * cDM + i];
    memout[b * cDM + i] = (1.f - zg) * ng + zg * mold;
    out[(size_t)(b * cL + stage) * cDU + i] = z[b * cDU + i];
  }
}

extern "C" void kernel_launch(void* const* d_in, const int* in_sizes, int n_in,
                              void* d_out, int out_size, void* d_ws, size_t ws_size,
                              hipStream_t stream) {
  const float* u    = (const float*)d_in[0];
  const float* sf   = (const float*)d_in[1];
  const float* sim  = (const float*)d_in[2];
  const float* mem0 = (const float*)d_in[3];
  const float* Wq   = (const float*)d_in[4];
  const float* Wk   = (const float*)d_in[5];
  const float* Wv   = (const float*)d_in[6];
  const float* sbw1 = (const float*)d_in[7];
  const float* sbb1 = (const float*)d_in[8];
  const float* sbw2 = (const float*)d_in[9];
  const float* sbb2 = (const float*)d_in[10];
  const float* logt = (const float*)d_in[11];
  const float* W_ih = (const float*)d_in[12];
  const float* b_ih = (const float*)d_in[13];
  const float* W_hh = (const float*)d_in[14];
  const float* b_hh = (const float*)d_in[15];
  float* out = (float*)d_out;
  float* ws  = (float*)d_ws;
  u16* ubf  = (u16*)((char*)d_ws + U_OFFB);
  u8* sim8  = (u8*)((char*)d_ws + S8_OFFB);

  const int use_ubf = (ws_size >= WS_NEED_U) ? 1 : 0;
  const int use_s8  = (ws_size >= WS_NEED_ALL) ? 1 : 0;

  k_init<<<1088, 256, 0, stream>>>(u, sf, mem0, Wq, Wk, sbw1, sbb1, sbw2, sbb2,
                                   ws, ubf, use_ubf);

  for (int stage = 0; stage < cL; ++stage) {
    float* mcur = ws + ((stage & 1) ? F_M1 : F_M0);
    float* mnxt = ws + ((stage & 1) ? F_M0 : F_M1);
    k_qk<<<1024, 256, 0, stream>>>(ws + F_A, mcur, ws + F_QK, ws + F_C);
    k_scores<<<512, 256, 0, stream>>>(ubf, u, ws + F_QK, ws + F_SB, sim8, sim,
                                      ws + F_PR, logt, stage == 0 ? 0.0f : cGAMMA,
                                      use_ubf, use_s8, ws + F_LG);
    k_overlap<<<1024, 256, 0, stream>>>(sim8, sim8, sim, ws + F_LG, use_s8,
                                        (stage == 0 && use_s8) ? 1 : 0, ws + F_OV);
    k_statcen<<<512, 256, 0, stream>>>(ws + F_OV, ws + F_LG, ws + F_UN,
                                       ubf, u, use_ubf,
                                       ws + F_Y, ws + F_PR, ws + F_SC, ws + F_C,
                                       stage == 0 ? 1 : 0);
    k_zyd<<<2048, 256, 0, stream>>>(ws + F_C, Wv, ubf, u, use_ubf,
                                    ws + F_UN, ws + F_Y, ws + F_Z, ws + F_SC, ws + F_SP);
    k_gru<<<1024, 256, 0, stream>>>(ws + F_Z, ws + F_SC, ws + F_SP, mcur, mnxt,
                                    W_ih, b_ih, W_hh, b_hh, out, stage);
  }
}